// Round 19
// baseline (223.890 us; speedup 1.0000x reference)
//
#include <hip/hip_runtime.h>
#include <hip/hip_bf16.h>

typedef __bf16 bf16;
typedef __bf16 bf16x4 __attribute__((ext_vector_type(4)));
typedef __bf16 bf16x8 __attribute__((ext_vector_type(8)));
typedef float  f32x4  __attribute__((ext_vector_type(4)));

#define KB 2
#define KS 2048
#define KD 1024
#define KH 16
#define KM (KB*KS)          // 4096 token rows
#define KQKVN 3072
#define KDF 4096

__device__ __forceinline__ f32x4 mfma16(bf16x8 a, bf16x8 b, f32x4 c) {
  return __builtin_amdgcn_mfma_f32_16x16x32_bf16(a, b, c, 0, 0, 0);
}

// raw v_exp_f32: computes 2^x (one TRANS op, no ln2 mul)
__device__ __forceinline__ float exp2_hw(float x) {
  float r;
  asm("v_exp_f32 %0, %1" : "=v"(r) : "v"(x));
  return r;
}

// async global->LDS, 16B per lane; LDS dest wave-uniform (HW adds lane*16)
__device__ __forceinline__ void g2l16(const bf16* g, bf16* l) {
  __builtin_amdgcn_global_load_lds(
      (const __attribute__((address_space(1))) unsigned int*)g,
      (__attribute__((address_space(3))) unsigned int*)l, 16, 0, 0);
}

// ---------------- fp32 -> bf16 elementwise ----------------
__global__ __launch_bounds__(256) void cvt_bf16_kernel(const float* __restrict__ in,
                                                       bf16* __restrict__ out, int n) {
  int i = (blockIdx.x * 256 + threadIdx.x) * 4;
  if (i >= n) return;
  f32x4 v = *reinterpret_cast<const f32x4*>(in + i);
  bf16x4 o;
  o[0] = (bf16)v[0]; o[1] = (bf16)v[1]; o[2] = (bf16)v[2]; o[3] = (bf16)v[3];
  *reinterpret_cast<bf16x4*>(out + i) = o;
}

// ---------------- fused W[K][N] f32 -> WT[N][K] bf16 transposes ----------------
struct WT4 { const float* src[4]; bf16* dst[4]; };

__global__ __launch_bounds__(256) void wtrans4_kernel(WT4 jobs) {
  __shared__ float tile[32][33];
  const float* W = jobs.src[blockIdx.z];
  bf16* WT = jobs.dst[blockIdx.z];
  const int n0 = blockIdx.x * 32, k0 = blockIdx.y * 32;
  const int tx = threadIdx.x & 31, ty = threadIdx.x >> 5;
#pragma unroll
  for (int j = ty; j < 32; j += 8) tile[j][tx] = W[(size_t)(k0 + j) * 1024 + n0 + tx];
  __syncthreads();
#pragma unroll
  for (int j = ty; j < 32; j += 8)
    WT[(size_t)(n0 + j) * 1024 + k0 + tx] = (bf16)tile[tx][j];
}

__global__ __launch_bounds__(256) void wtrans_big_kernel(const float* __restrict__ w1,
                                                         bf16* __restrict__ w1T,
                                                         const float* __restrict__ w2,
                                                         bf16* __restrict__ w2T) {
  __shared__ float tile[32][33];
  const float* W; bf16* WT; int K, N, n0, k0;
  if (blockIdx.z == 0) {
    W = w1; WT = w1T; K = 1024; N = 4096;
    n0 = blockIdx.x * 32; k0 = blockIdx.y * 32;
  } else {
    W = w2; WT = w2T; K = 4096; N = 1024;
    n0 = blockIdx.y * 32; k0 = blockIdx.x * 32;
  }
  const int tx = threadIdx.x & 31, ty = threadIdx.x >> 5;
#pragma unroll
  for (int j = ty; j < 32; j += 8) tile[j][tx] = W[(size_t)(k0 + j) * N + n0 + tx];
  __syncthreads();
#pragma unroll
  for (int j = ty; j < 32; j += 8) WT[(size_t)(n0 + j) * K + k0 + tx] = (bf16)tile[tx][j];
}

// ---------------- deep-pipeline GEMM: 256x256, BK=32, ring-2, 64KB LDS ----------
// 8 waves (2Mx4N), 512 thr. 64KB LDS -> 2 blocks/CU = 16 waves/CU (TLP hides the
// barrier drains; R18's attn lesson applied to GEMM). Per-output work identical
// to the BK=64 version (same loads, same MFMA, same read/MFMA ratio).
// Sync (R12-R17-proven two-barrier form):
//  RAW: head stage(t+1) (4 loads) + vmcnt(4) (in-order retirement => all 4
//       tile-t loads landed) + s_barrier (all waves).
//  WAR: tail barrier — every wave's tile-t LDS reads are consumed by MFMAs
//       before it; buf[t&1] is only re-staged at iter t+1's head (after it).
// 4-slot XOR swizzle (BK=32 rows = 64B = 4 chunks; proven R4-R7).
// QKVPACK epilogue folds kvpack into the QKV GEMM (R13-proven derivation).
struct P4 { bf16* p[4]; };

template <typename OUT_T, bool RELU, bool HAS_BIAS, bool SPLITK, bool QKVPACK>
__global__ __launch_bounds__(512, 2) void gemm8p(const bf16* __restrict__ A,
                                                 const bf16* __restrict__ BT,
                                                 OUT_T* __restrict__ C, P4 pr,
                                                 const float* __restrict__ bias,
                                                 int M, int N, int K, int Kslice) {
  extern __shared__ __align__(16) bf16 sm[];      // [2][A 8192 | B 8192] = 64 KiB
  const int tid = threadIdx.x, lane = tid & 63, w = tid >> 6;
  const int wr = w >> 2, wc = w & 3;
  const int gx = gridDim.x;
  const int nwg = gx * gridDim.y;
  int flat = blockIdx.y * gx + blockIdx.x;
  flat = (flat & 7) * (nwg >> 3) + (flat >> 3);   // XCD-chunked (nwg%8==0)
  const int bn = (flat % gx) * 256;
  const int bm = (flat / gx) * 256;
  const int z = blockIdx.z;
  const int NT = (SPLITK ? Kslice : K) >> 5;      // BK=32
  const int lr = lane & 15, hi = lane >> 4;
  const bf16* Abase = A + (size_t)bm * K + (SPLITK ? z * Kslice : 0);
  const bf16* Bbase = BT + (size_t)bn * K + (SPLITK ? z * Kslice : 0);
  // chunk u in [0,1024): row = u>>2 (64B rows), LDS slot u&3 holds global
  // slot (u&3)^(row&3). Wave covers 64 consecutive chunks -> lane-linear dest.
  int srow[2], scol[2];
#pragma unroll
  for (int j = 0; j < 2; j++) {
    const int u = j * 512 + w * 64 + lane;
    srow[j] = u >> 2;
    scol[j] = ((u & 3) ^ ((u >> 2) & 3)) * 8;
  }
  auto stageQ = [&](int t) {
    bf16* dst = sm + (size_t)(t & 1) * 16384;
    const int k0 = t * 32;
#pragma unroll
    for (int j = 0; j < 2; j++) {
      bf16* d = dst + (j * 512 + w * 64) * 8;
      g2l16(Abase + (size_t)srow[j] * K + k0 + scol[j], d);
      g2l16(Bbase + (size_t)srow[j] * K + k0 + scol[j], d + 8192);
    }
  };
  f32x4 acc[8][4] = {};
  stageQ(0);                                      // 4 loads in flight
  for (int t = 0; t < NT; t++) {
    if (t + 1 < NT) {
      stageQ(t + 1);
      asm volatile("s_waitcnt vmcnt(4)" ::: "memory");
    } else {
      asm volatile("s_waitcnt vmcnt(0)" ::: "memory");
    }
    __builtin_amdgcn_sched_barrier(0);
    __builtin_amdgcn_s_barrier();                 // RAW: tile t ready, all waves
    __builtin_amdgcn_sched_barrier(0);
    const char* sa = (const char*)(sm + (size_t)(t & 1) * 16384);
    const char* sb = sa + 16384;
    bf16x8 af[8], bfr[4];
#pragma unroll
    for (int mf = 0; mf < 8; mf++) {
      const int row = wr * 128 + mf * 16 + lr;
      af[mf] = *(const bf16x8*)(sa + row * 64 + ((hi ^ (row & 3)) * 16));
    }
#pragma unroll
    for (int nf = 0; nf < 4; nf++) {
      const int row = wc * 64 + nf * 16 + lr;
      bfr[nf] = *(const bf16x8*)(sb + row * 64 + ((hi ^ (row & 3)) * 16));
    }
    __builtin_amdgcn_s_setprio(1);
#pragma unroll
    for (int mf = 0; mf < 8; mf++)
#pragma unroll
      for (int nf = 0; nf < 4; nf++)
        acc[mf][nf] = mfma16(af[mf], bfr[nf], acc[mf][nf]);
    __builtin_amdgcn_s_setprio(0);
    // WAR: all waves' tile-t reads consumed before buf[t&1] is re-staged
    __builtin_amdgcn_sched_barrier(0);
    __builtin_amdgcn_s_barrier();
    __builtin_amdgcn_sched_barrier(0);
  }
  const int rg = hi * 4, cl = lr;
  if (QKVPACK && (bn >> 10) == 1) {
    // K -> kp[bh][s][64]
    bf16* kp_ = pr.p[0];
    const int b_ = bm >> 11;
    const int sb_ = (bm & 2047) + wr * 128;
#pragma unroll
    for (int mf = 0; mf < 8; mf++)
#pragma unroll
      for (int nf = 0; nf < 4; nf++) {
        const int col_loc = (bn & 1023) + wc * 64 + nf * 16 + cl;
        const int hh = col_loc >> 6, dd = col_loc & 63;
        bf16* base = kp_ + (size_t)(b_ * 16 + hh) * (KS * 64) + dd;
#pragma unroll
        for (int i = 0; i < 4; i++)
          base[(size_t)(sb_ + mf * 16 + rg + i) * 64] = (bf16)acc[mf][nf][i];
      }
  } else if (QKVPACK && (bn >> 10) == 2) {
    // V -> vt[bh][d][s], slot-permuted (R13 derivation)
    bf16* vt_ = pr.p[1];
    const int b_ = bm >> 11;
    const int sb_ = (bm & 2047) + wr * 128;
    const int pib = ((hi & 2) << 3) | ((hi & 1) << 3);
#pragma unroll
    for (int mf = 0; mf < 8; mf++) {
      const int s_hi = sb_ + (mf >> 2) * 64;
      const int pibase = pib | ((mf & 2) << 4) | ((mf & 1) << 2);
#pragma unroll
      for (int nf = 0; nf < 4; nf++) {
        const int col_loc = (bn & 1023) + wc * 64 + nf * 16 + cl;
        const int hh = col_loc >> 6, dd = col_loc & 63;
        bf16x4 o;
#pragma unroll
        for (int i = 0; i < 4; i++) o[i] = (bf16)acc[mf][nf][i];
        *(bf16x4*)(vt_ + (size_t)(b_ * 16 + hh) * (64 * KS) +
                   (size_t)dd * KS + s_hi + pibase) = o;
      }
    }
  } else if (SPLITK) {
    bf16* P = pr.p[z];
#pragma unroll
    for (int mf = 0; mf < 8; mf++)
#pragma unroll
      for (int nf = 0; nf < 4; nf++) {
        const int col = bn + wc * 64 + nf * 16 + cl;
#pragma unroll
        for (int i = 0; i < 4; i++) {
          const int row = bm + wr * 128 + mf * 16 + rg + i;
          P[(size_t)row * N + col] = (bf16)acc[mf][nf][i];
        }
      }
  } else {
#pragma unroll
    for (int mf = 0; mf < 8; mf++)
#pragma unroll
      for (int nf = 0; nf < 4; nf++) {
        const int col = bn + wc * 64 + nf * 16 + cl;
        float bv = 0.f;
        if (HAS_BIAS) bv = bias[col];
#pragma unroll
        for (int i = 0; i < 4; i++) {
          const int row = bm + wr * 128 + mf * 16 + rg + i;
          float v = acc[mf][nf][i] + bv;
          if (RELU) v = fmaxf(v, 0.f);
          C[(size_t)row * N + col] = (OUT_T)v;
        }
      }
  }
}

// ---------------- old 2-phase GEMM (kept for Wo: short K, N=1024) ----------------
template <typename OUT_T, bool RELU, bool HAS_BIAS, int BN>
__global__ __launch_bounds__(256) void gemm_bt(const bf16* __restrict__ A,
                                               const bf16* __restrict__ BT,
                                               OUT_T* __restrict__ C,
                                               const float* __restrict__ bias,
                                               int M, int N, int K) {
  constexpr int NF = BN / 32;
  __shared__ __align__(16) bf16 sa[2][128 * 32];
  __shared__ __align__(16) bf16 sb[2][BN * 32];
  const int t = threadIdx.x, lane = t & 63, w = t >> 6;
  const int gx = gridDim.x;
  const int nwg = gx * gridDim.y;
  int flat = blockIdx.y * gx + blockIdx.x;
  if ((nwg & 7) == 0) flat = (flat & 7) * (nwg >> 3) + (flat >> 3);
  const int bn = (flat % gx) * BN;
  const int bm = (flat / gx) * 128;
  const int wr = w >> 1, wc = w & 1;
  const int wcol = wc * (BN / 2);
  const int lr = lane & 15, lk = (lane >> 4) * 8;
  const int srow = w * 16 + (lane >> 2);
  const int scol = (lane & 3) * 8;
  f32x4 acc[4][NF] = {};
  const int NT = K >> 5;
  auto stage = [&](int kt, int buf) {
#pragma unroll
    for (int i = 0; i < 2; i++)
      g2l16(A + (size_t)(bm + i * 64 + srow) * K + kt * 32 + scol,
            &sa[buf][(i * 64 + w * 16) * 32]);
#pragma unroll
    for (int i = 0; i < BN / 64; i++)
      g2l16(BT + (size_t)(bn + i * 64 + srow) * K + kt * 32 + scol,
            &sb[buf][(i * 64 + w * 16) * 32]);
  };
  stage(0, 0);
  int cur = 0;
  for (int kt = 0; kt < NT; kt++) {
    __syncthreads();
    if (kt + 1 < NT) stage(kt + 1, cur ^ 1);
    bf16x8 af[4], bfr[NF];
#pragma unroll
    for (int m = 0; m < 4; m++)
      af[m] = *(const bf16x8*)&sa[cur][(wr * 64 + m * 16 + lr) * 32 + lk];
#pragma unroll
    for (int n = 0; n < NF; n++)
      bfr[n] = *(const bf16x8*)&sb[cur][(wcol + n * 16 + lr) * 32 + lk];
#pragma unroll
    for (int m = 0; m < 4; m++)
#pragma unroll
      for (int n = 0; n < NF; n++)
        acc[m][n] = mfma16(af[m], bfr[n], acc[m][n]);
    cur ^= 1;
  }
  const int rg = (lane >> 4) * 4, cl = lane & 15;
#pragma unroll
  for (int m = 0; m < 4; m++)
#pragma unroll
    for (int n = 0; n < NF; n++) {
      const int col = bn + wcol + n * 16 + cl;
      float bv = 0.f;
      if (HAS_BIAS) bv = bias[col];
#pragma unroll
      for (int i = 0; i < 4; i++) {
        const int row = bm + wr * 64 + m * 16 + rg + i;
        float v = acc[m][n][i] + bv;
        if (RELU) v = fmaxf(v, 0.f);
        C[(size_t)row * N + col] = (OUT_T)v;
      }
    }
}

// ---------------- flash attention: swapped QK^T, in-register P, ring-4 ----------
// (R18-proven, unchanged.) 8 waves x 16 q-rows (512 thr), 16 waves/CU.
__global__ __launch_bounds__(512) void attn_kernel(const bf16* __restrict__ qkv,
                                                   const bf16* __restrict__ kp,
                                                   const bf16* __restrict__ vt,
                                                   bf16* __restrict__ ctx) {
  __shared__ __align__(16) bf16 ksm[4][64 * 64];
  __shared__ __align__(16) bf16 vsm[4][64 * 64];
  const int t = threadIdx.x, lane = t & 63, w = t >> 6;   // w in [0,8)
  const int flat = blockIdx.y * 16 + blockIdx.x;
  const int xcd = flat & 7, jj = flat >> 3;
  const int bh = xcd + 8 * (jj >> 4);              // all 16 q-blocks of a head on 1 XCD
  const int qb = jj & 15;
  const int b = bh >> 4, h = bh & 15;
  const int qbase = qb * 128 + w * 16;
  const int lr = lane & 15, hi = lane >> 4;
  const int lk = hi * 8, rg = hi * 4, cl = lr;

  // Q fragments, pre-scaled by 0.125*log2(e) so scores feed v_exp_f32 directly
  bf16x8 aq[2];
#pragma unroll
  for (int kk = 0; kk < 2; kk++) {
    bf16x8 v = *reinterpret_cast<const bf16x8*>(
        &qkv[(size_t)(b * KS + qbase + lr) * KQKVN + h * 64 + kk * 32 + lk]);
#pragma unroll
    for (int e = 0; e < 8; e++) v[e] = (bf16)((float)v[e] * 0.18033688f);
    aq[kk] = v;
  }
  bf16x8 ones;
#pragma unroll
  for (int j = 0; j < 8; j++) ones[j] = (bf16)1.0f;

  const bf16* kpb = kp + (size_t)bh * KS * 64;
  const bf16* vtb = vt + (size_t)bh * 64 * KS;

  // 512 lanes cover each 8KB (64x64 bf16) tile in one shot: 1 K + 1 V load/lane
  auto stageKV = [&](int tt) {
    const int kt0 = tt * 64;
    bf16* kd = &ksm[tt & 3][0] + w * 512;            // wave-uniform dest
    bf16* vd = &vsm[tt & 3][0] + w * 512;
    const int q = w * 1024 + (lane << 4);            // this lane's LDS byte
    const int row = q >> 7;
    const int slot = ((q >> 4) & 7) ^ (row & 7);     // inverse-swizzled source
    g2l16(kpb + (size_t)(kt0 + row) * 64 + slot * 8, kd);
    g2l16(vtb + (size_t)row * KS + kt0 + slot * 8,   vd);
  };

  f32x4 accd[4] = {};
  f32x4 lsumv = {};

  stageKV(0); stageKV(1); stageKV(2);                 // 6 loads/lane in flight
  const int NT = KS / 64;                             // 32
  for (int tt = 0; tt < NT; tt++) {
    const int rem = NT - 1 - tt;
    if (rem >= 2)      asm volatile("s_waitcnt vmcnt(4)" ::: "memory");
    else if (rem == 1) asm volatile("s_waitcnt vmcnt(2)" ::: "memory");
    else               asm volatile("s_waitcnt vmcnt(0)" ::: "memory");
    __builtin_amdgcn_sched_barrier(0);
    __builtin_amdgcn_s_barrier();                     // RAW: tile tt ready
    __builtin_amdgcn_sched_barrier(0);
    if (tt + 3 < NT) stageKV(tt + 3);
    const char* kb = (const char*)&ksm[tt & 3][0];
    const char* vb = (const char*)&vsm[tt & 3][0];
    // K fragments (A-operand: rows = keys)
    bf16x8 bk[4][2];
#pragma unroll
    for (int n = 0; n < 4; n++)
#pragma unroll
      for (int kk = 0; kk < 2; kk++) {
        const int row = n * 16 + lr;
        bk[n][kk] = *(const bf16x8*)(kb + row * 128 +
                                     ((kk * 64 + hi * 16) ^ ((row & 7) << 4)));
      }
    // swapped QK^T: D[key][q] — lane holds 16 keys for its own q = lr
    f32x4 sc[4] = {};
    __builtin_amdgcn_s_setprio(1);
#pragma unroll
    for (int n = 0; n < 4; n++)
#pragma unroll
      for (int kk = 0; kk < 2; kk++)
        sc[n] = mfma16(bk[n][kk], aq[kk], sc[n]);
    __builtin_amdgcn_s_setprio(0);
    // p = 2^score in regs; build PV A-fragments directly
    bf16x8 pa[2];
    {
      float p[4][4];
#pragma unroll
      for (int n = 0; n < 4; n++)
#pragma unroll
        for (int i = 0; i < 4; i++)
          p[n][i] = exp2_hw(sc[n][i]);
#pragma unroll
      for (int kk = 0; kk < 2; kk++) {
        bf16x8 v;
#pragma unroll
        for (int j = 0; j < 8; j++) v[j] = (bf16)p[kk * 2 + (j >> 2)][j & 3];
        pa[kk] = v;
      }
    }
    // V fragments (B-operand, slot-permuted rows) + PV + MFMA row-sums
    bf16x8 bv[4][2];
#pragma unroll
    for (int dt = 0; dt < 4; dt++)
#pragma unroll
      for (int kk = 0; kk < 2; kk++) {
        const int row = dt * 16 + lr;
        bv[dt][kk] = *(const bf16x8*)(vb + row * 128 +
                                      ((kk * 64 + hi * 16) ^ ((row & 7) << 4)));
      }
    __builtin_amdgcn_s_setprio(1);
#pragma unroll
    for (int dt = 0; dt < 4; dt++)
#pragma unroll
      for (int kk = 0; kk < 2; kk++)
        accd[dt] = mfma16(pa[kk], bv[dt][kk], accd[dt]);
    lsumv = mfma16(pa[0], ones, lsumv);
    lsumv = mfma16(pa[1], ones, lsumv);
    __builtin_amdgcn_s_setprio(0);
  }
  // lsumv in C-layout: lane's lsumv[i] = rowsum for q = rg+i
#pragma unroll
  for (int dt = 0; dt < 4; dt++)
#pragma unroll
    for (int i = 0; i < 4; i++)
      ctx[(size_t)(b * KS + qbase + rg + i) * KD + h * 64 + dt * 16 + cl] =
          (bf16)(accd[dt][i] / lsumv[i]);
}

// ---------------- residual add + LayerNorm ----------------
// a + b -> LN; each of a, b, out independently bf16 or f32
template <bool ABF, bool BBF, bool OBF>
__global__ __launch_bounds__(256) void ln_kernel(const void* __restrict__ aptr,
                                                 const void* __restrict__ bptr,
                                                 const float* __restrict__ g,
                                                 const float* __restrict__ bet,
                                                 void* __restrict__ outp) {
  const int row = blockIdx.x;
  const int t = threadIdx.x;
  const int lane = t & 63, wid = t >> 6;
  float v[4];
  {
    float a[4], bb[4];
    if (ABF) {
      bf16x4 av = *reinterpret_cast<const bf16x4*>(
          (const bf16*)aptr + (size_t)row * KD + t * 4);
#pragma unroll
      for (int j = 0; j < 4; j++) a[j] = (float)av[j];
    } else {
      f32x4 av = *reinterpret_cast<const f32x4*>(
          (const float*)aptr + (size_t)row * KD + t * 4);
#pragma unroll
      for (int j = 0; j < 4; j++) a[j] = av[j];
    }
    if (BBF) {
      bf16x4 bv = *reinterpret_cast<const bf16x4*>(
          (const bf16*)bptr + (size_t)row * KD + t * 4);
#pragma unroll
      for (int j = 0; j < 4; j++) bb[j] = (float)bv[j];
    } else {
      f32x4 bv = *reinterpret_cast<const f32x4*>(
          (const float*)bptr + (size_t)row * KD + t * 4);
#pragma unroll
      for (int j = 0; j < 4; j++) bb[j] = bv[j];
    }
#pragma unroll
    for (int j = 0; j < 4; j++) v[j] = a[j] + bb[j];
  }
  float s = 0.f, s2 = 0.f;
#pragma unroll
  for (int j = 0; j < 4; j++) { s += v[j]; s2 += v[j] * v[j]; }
#pragma unroll
  for (int off = 32; off; off >>= 1) {
    s += __shfl_xor(s, off, 64);
    s2 += __shfl_xor(s2, off, 64);
  }
  __shared__ float red[8];
  if (lane == 0) { red[wid] = s; red[wid + 4] = s2; }
  __syncthreads();
  s = red[0] + red[1] + red[2] + red[3];
  s2 = red[4] + red[5] + red[6] + red[7];
  const float mu = s * (1.f / KD);
  const float var = s2 * (1.f / KD) - mu * mu;
  const float rs = rsqrtf(var + 1e-5f);
  if (OBF) {
    bf16x4 o;
#pragma unroll
    for (int j = 0; j < 4; j++)
      o[j] = (bf16)((v[j] - mu) * rs * g[t * 4 + j] + bet[t * 4 + j]);
    *reinterpret_cast<bf16x4*>((bf16*)outp + (size_t)row * KD + t * 4) = o;
  } else {
    f32x4 o;
#pragma unroll
    for (int j = 0; j < 4; j++)
      o[j] = (v[j] - mu) * rs * g[t * 4 + j] + bet[t * 4 + j];
    *reinterpret_cast<f32x4*>((float*)outp + (size_t)row * KD + t * 4) = o;
  }
}

// ---------------- LN2 fused with FFN2 split-K reduce + bias ----------------
// out = LN(h + p0+p1+p2+p3 + b2)
__global__ __launch_bounds__(256) void ln2_fused_kernel(const bf16* __restrict__ hh,
                                                        const bf16* __restrict__ p0,
                                                        const bf16* __restrict__ p1,
                                                        const bf16* __restrict__ p2,
                                                        const bf16* __restrict__ p3,
                                                        const float* __restrict__ b2,
                                                        const float* __restrict__ g,
                                                        const float* __restrict__ bet,
                                                        float* __restrict__ outp) {
  const int row = blockIdx.x;
  const int t = threadIdx.x;
  const int lane = t & 63, wid = t >> 6;
  const size_t base = (size_t)row * KD + t * 4;
  bf16x4 hv = *(const bf16x4*)(hh + base);
  bf16x4 a0 = *(const bf16x4*)(p0 + base);
  bf16x4 a1 = *(const bf16x4*)(p1 + base);
  bf16x4 a2 = *(const bf16x4*)(p2 + base);
  bf16x4 a3 = *(const bf16x4*)(p3 + base);
  f32x4 bv = *(const f32x4*)(b2 + t * 4);
  float v[4];
#pragma unroll
  for (int j = 0; j < 4; j++)
    v[j] = (float)hv[j] + (float)a0[j] + (float)a1[j] + (float)a2[j] + (float)a3[j] + bv[j];
  float s = 0.f, s2 = 0.f;
#pragma unroll
  for (int j = 0; j < 4; j++) { s += v[j]; s2 += v[j] * v[j]; }
#pragma unroll
  for (int off = 32; off; off >>= 1) {
    s += __shfl_xor(s, off, 64);
    s2 += __shfl_xor(s2, off, 64);
  }
  __shared__ float red[8];
  if (lane == 0) { red[wid] = s; red[wid + 4] = s2; }
  __syncthreads();
  s = red[0] + red[1] + red[2] + red[3];
  s2 = red[4] + red[5] + red[6] + red[7];
  const float mu = s * (1.f / KD);
  const float var = s2 * (1.f / KD) - mu * mu;
  const float rs = rsqrtf(var + 1e-5f);
  f32x4 o;
#pragma unroll
  for (int j = 0; j < 4; j++)
    o[j] = (v[j] - mu) * rs * g[t * 4 + j] + bet[t * 4 + j];
  *reinterpret_cast<f32x4*>(outp + base) = o;
}

extern "C" void kernel_launch(void* const* d_in, const int* in_sizes, int n_in,
                              void* d_out, int out_size, void* d_ws, size_t ws_size,
                              hipStream_t stream) {
  const float* x     = (const float*)d_in[0];
  const float* wq    = (const float*)d_in[1];
  const float* wk    = (const float*)d_in[2];
  const float* wv    = (const float*)d_in[3];
  const float* wo    = (const float*)d_in[4];
  const float* w1    = (const float*)d_in[5];
  const float* b1    = (const float*)d_in[6];
  const float* w2    = (const float*)d_in[7];
  const float* b2    = (const float*)d_in[8];
  const float* ln1g  = (const float*)d_in[9];
  const float* ln1b  = (const float*)d_in[10];
  const float* ln2g  = (const float*)d_in[11];
  const float* ln2b  = (const float*)d_in[12];
  float* out = (float*)d_out;

  char* ws = (char*)d_ws;
  // Alias audit (write -> read order; every region rewritten before read):
  // [0     , 8.39M)  x_bf (1->2,6) -> FFN2 pr0 (8->9)
  // [8.39M ,14.68M)  wqkvT (1->2) ; h_bf [8.39,16.78) (6->7,9)
  // [14.68M,16.78M)  woT (1->5)
  // [16.78M,25.17M)  w1T (1->7) -> FFN2 pr1 (8->9)
  // [25.17M,33.55M)  w2T (1->8)
  // [33.55M,58.72M)  qkv Q-cols (2->4) -> ffn1 [33.55,67.11) (7->8)
  // [58.72M,67.11M)  kp (2->4)
  // [67.11M,75.50M)  vt (2->4) -> FFN2 pr2 (8->9)
  // [75.50M,83.89M)  ctx (4->5) -> FFN2 pr3 (8->9)
  // [83.89M,92.27M)  proj_bf (5->6)
  bf16*  x_bf   = (bf16*)(ws + 0);
  bf16*  wqkvT  = (bf16*)(ws + 8388608);
  bf16*  woT    = (bf16*)(ws + 14680064);
  bf16*  w1T    = (bf16*)(ws + 16777216);
  bf16*  w2T    = (bf16*)(ws + 25165824);
  bf16*  qkv    = (bf16*)(ws + 33554432);
  bf16*  kp     = (bf16*)(ws + 58720256);
  bf16*  vt     = (bf16*)(ws + 67108864);
  bf16*  ctx    = (bf16*)(ws + 75497472);
  bf16*  proj_bf= (bf16*)(ws + 83886080);
  bf16*  h_bf   = (bf16*)(ws + 8388608);
  bf16*  ffn1   = qkv;
  P4 pk;                                   // QKV pack targets
  pk.p[0] = kp; pk.p[1] = vt; pk.p[2] = nullptr; pk.p[3] = nullptr;
  P4 pr;                                   // FFN2 split-K partials
  pr.p[0] = (bf16*)(ws + 0);
  pr.p[1] = (bf16*)(ws + 16777216);
  pr.p[2] = (bf16*)(ws + 67108864);
  pr.p[3] = (bf16*)(ws + 75497472);
  P4 pzero = {};

  // 1) conversions / transposes
  cvt_bf16_kernel<<<dim3(KM * KD / 1024), 256, 0, stream>>>(x, x_bf, KM * KD);
  WT4 jobs;
  jobs.src[0] = wq; jobs.src[1] = wk; jobs.src[2] = wv; jobs.src[3] = wo;
  jobs.dst[0] = wqkvT;
  jobs.dst[1] = wqkvT + 1024 * 1024;
  jobs.dst[2] = wqkvT + 2048 * 1024;
  jobs.dst[3] = woT;
  wtrans4_kernel<<<dim3(32, 32, 4), 256, 0, stream>>>(jobs);
  wtrans_big_kernel<<<dim3(128, 32, 2), 256, 0, stream>>>(w1, w1T, w2, w2T);

  // 2) QKV projection with fused K/V repack (Q->qkv, K->kp, V->vt permuted)
  gemm8p<bf16, false, false, false, true>
      <<<dim3(KQKVN / 256, KM / 256, 1), 512, 65536, stream>>>(
      x_bf, wqkvT, qkv, pk, nullptr, KM, KQKVN, KD, KD);

  // 4) flash attention (8 waves x 16 q-rows, ring-4, 16 waves/CU)
  attn_kernel<<<dim3(KS / 128, KB * KH), 512, 0, stream>>>(qkv, kp, vt, ctx);

  // 5) Wo projection: 2-phase BN=64 (512 blocks) -> proj_bf (bf16)
  gemm_bt<bf16, false, false, 64><<<dim3(KD / 64, KM / 128), 256, 0, stream>>>(
      ctx, woT, proj_bf, nullptr, KM, KD, KD);

  // 6) LN1: h = LN(x_bf + proj_bf) -> h_bf
  ln_kernel<true, true, true><<<dim3(KM), 256, 0, stream>>>(
      x_bf, proj_bf, ln1g, ln1b, h_bf);

  // 7) FFN1: BK=32 ring-2 deep-pipeline, 256 blocks (2/CU)
  gemm8p<bf16, true, true, false, false>
      <<<dim3(KDF / 256, KM / 256, 1), 512, 65536, stream>>>(
      h_bf, w1T, ffn1, pzero, b1, KM, KDF, KD, KD);

  // 8) FFN2: split-K=4 (4x16x4 = 256 blocks, Kslice=1024) -> bf16 partials
  gemm8p<bf16, false, false, true, false>
      <<<dim3(KD / 256, KM / 256, 4), 512, 65536, stream>>>(
      ffn1, w2T, (bf16*)nullptr, pr, nullptr, KM, KD, KDF, KDF / 4);

  // 9) LN2 fused with split-K reduce + bias
  ln2_fused_kernel<<<dim3(KM), 256, 0, stream>>>(
      h_bf, pr.p[0], pr.p[1], pr.p[2], pr.p[3], b2, ln2g, ln2b, out);
}

// Round 20
// 211.333 us; speedup vs baseline: 1.0594x; 1.0594x over previous
//
#include <hip/hip_runtime.h>
#include <hip/hip_bf16.h>

typedef __bf16 bf16;
typedef __bf16 bf16x4 __attribute__((ext_vector_type(4)));
typedef __bf16 bf16x8 __attribute__((ext_vector_type(8)));
typedef float  f32x4  __attribute__((ext_vector_type(4)));

#define KB 2
#define KS 2048
#define KD 1024
#define KH 16
#define KM (KB*KS)          // 4096 token rows
#define KQKVN 3072
#define KDF 4096

__device__ __forceinline__ f32x4 mfma16(bf16x8 a, bf16x8 b, f32x4 c) {
  return __builtin_amdgcn_mfma_f32_16x16x32_bf16(a, b, c, 0, 0, 0);
}

// raw v_exp_f32: computes 2^x (one TRANS op, no ln2 mul)
__device__ __forceinline__ float exp2_hw(float x) {
  float r;
  asm("v_exp_f32 %0, %1" : "=v"(r) : "v"(x));
  return r;
}

// async global->LDS, 16B per lane; LDS dest wave-uniform (HW adds lane*16)
__device__ __forceinline__ void g2l16(const bf16* g, bf16* l) {
  __builtin_amdgcn_global_load_lds(
      (const __attribute__((address_space(1))) unsigned int*)g,
      (__attribute__((address_space(3))) unsigned int*)l, 16, 0, 0);
}

// ---------------- fp32 -> bf16 elementwise ----------------
__global__ __launch_bounds__(256) void cvt_bf16_kernel(const float* __restrict__ in,
                                                       bf16* __restrict__ out, int n) {
  int i = (blockIdx.x * 256 + threadIdx.x) * 4;
  if (i >= n) return;
  f32x4 v = *reinterpret_cast<const f32x4*>(in + i);
  bf16x4 o;
  o[0] = (bf16)v[0]; o[1] = (bf16)v[1]; o[2] = (bf16)v[2]; o[3] = (bf16)v[3];
  *reinterpret_cast<bf16x4*>(out + i) = o;
}

// ---------------- fused W[K][N] f32 -> WT[N][K] bf16 transposes ----------------
struct WT4 { const float* src[4]; bf16* dst[4]; };

__global__ __launch_bounds__(256) void wtrans4_kernel(WT4 jobs) {
  __shared__ float tile[32][33];
  const float* W = jobs.src[blockIdx.z];
  bf16* WT = jobs.dst[blockIdx.z];
  const int n0 = blockIdx.x * 32, k0 = blockIdx.y * 32;
  const int tx = threadIdx.x & 31, ty = threadIdx.x >> 5;
#pragma unroll
  for (int j = ty; j < 32; j += 8) tile[j][tx] = W[(size_t)(k0 + j) * 1024 + n0 + tx];
  __syncthreads();
#pragma unroll
  for (int j = ty; j < 32; j += 8)
    WT[(size_t)(n0 + j) * 1024 + k0 + tx] = (bf16)tile[tx][j];
}

__global__ __launch_bounds__(256) void wtrans_big_kernel(const float* __restrict__ w1,
                                                         bf16* __restrict__ w1T,
                                                         const float* __restrict__ w2,
                                                         bf16* __restrict__ w2T) {
  __shared__ float tile[32][33];
  const float* W; bf16* WT; int K, N, n0, k0;
  if (blockIdx.z == 0) {
    W = w1; WT = w1T; K = 1024; N = 4096;
    n0 = blockIdx.x * 32; k0 = blockIdx.y * 32;
  } else {
    W = w2; WT = w2T; K = 4096; N = 1024;
    n0 = blockIdx.y * 32; k0 = blockIdx.x * 32;
  }
  const int tx = threadIdx.x & 31, ty = threadIdx.x >> 5;
#pragma unroll
  for (int j = ty; j < 32; j += 8) tile[j][tx] = W[(size_t)(k0 + j) * N + n0 + tx];
  __syncthreads();
#pragma unroll
  for (int j = ty; j < 32; j += 8) WT[(size_t)(n0 + j) * K + k0 + tx] = (bf16)tile[tx][j];
}

// ---------------- 4-phase deep-pipeline GEMM: 256x256, BK=64, ring-2 -------------
// (R12-R18 proven.) Minimal barriers: RAW phase-0 vmcnt(4)+barrier,
// WAR tile-end barrier. QKVPACK epilogue folds kvpack into the QKV GEMM:
// reg 0 = Q -> C (qkv, stride N), reg 1 = K -> kp[bh][s][64], reg 2 = V ->
// vt[bh][d][s] slot-permuted: key k = (mf&3)*16 + hi*4 + i -> position
// pi = ((mf&2)<<4)|((hi&2)<<3)|((hi&1)<<3)|((mf&1)<<2) + i.
struct P4 { bf16* p[4]; };

template <typename OUT_T, bool RELU, bool HAS_BIAS, bool SPLITK, bool QKVPACK>
__global__ __launch_bounds__(512, 2) void gemm8p(const bf16* __restrict__ A,
                                                 const bf16* __restrict__ BT,
                                                 OUT_T* __restrict__ C, P4 pr,
                                                 const float* __restrict__ bias,
                                                 int M, int N, int K, int Kslice) {
  extern __shared__ __align__(16) bf16 sm[];      // [2][A 16384 | B 16384] elems
  const int tid = threadIdx.x, lane = tid & 63, w = tid >> 6;
  const int wr = w >> 2, wc = w & 3;
  const int gx = gridDim.x;
  const int nwg = gx * gridDim.y;
  int flat = blockIdx.y * gx + blockIdx.x;
  flat = (flat & 7) * (nwg >> 3) + (flat >> 3);   // XCD-chunked (nwg%8==0)
  const int bn = (flat % gx) * 256;
  const int bm = (flat / gx) * 256;
  const int z = blockIdx.z;
  const int NT = (SPLITK ? Kslice : K) >> 6;      // BK=64
  const int lr = lane & 15, hi = lane >> 4;
  const int sqrow = tid >> 3;                     // 0..63, row within quarter
  const int sslot = tid & 7;
  const bf16* Abase = A + (size_t)bm * K + (SPLITK ? z * Kslice : 0);
  const bf16* Bbase = BT + (size_t)bn * K + (SPLITK ? z * Kslice : 0);
  // LDS[row][slot] = G[row][slot ^ (row&7)] (16B chunks); dest lane-linear.
  auto stageQ = [&](int t, int p) {
    const int row = p * 64 + sqrow;
    const int col = (sslot ^ (row & 7)) * 8;
    bf16* dst = sm + (size_t)(t & 1) * 32768 + p * 4096 + w * 512;
    g2l16(Abase + (size_t)row * K + t * 64 + col, dst);
    g2l16(Bbase + (size_t)row * K + t * 64 + col, dst + 16384);
  };
  f32x4 acc[8][4] = {};
  stageQ(0, 0); stageQ(0, 1); stageQ(0, 2); stageQ(0, 3);   // 8 loads in flight
  for (int t = 0; t < NT; t++) {
    const char* sa = (const char*)(sm + (size_t)(t & 1) * 32768);
    const char* sb = sa + 32768;
    // head: issue Q0,Q1 of t+1, then wait for all tile-t loads
    if (t + 1 < NT) {
      stageQ(t + 1, 0);
      stageQ(t + 1, 1);
      asm volatile("s_waitcnt vmcnt(4)" ::: "memory");
    } else {
      asm volatile("s_waitcnt vmcnt(0)" ::: "memory");
    }
    __builtin_amdgcn_sched_barrier(0);
    __builtin_amdgcn_s_barrier();                 // RAW: tile t ready, all waves
    __builtin_amdgcn_sched_barrier(0);
    if (t + 1 < NT) { stageQ(t + 1, 2); stageQ(t + 1, 3); }
    bf16x8 af[4], bfr[4];
    // ---- group 0: M-half 0, kk=0 ----
#pragma unroll
    for (int mfp = 0; mfp < 4; mfp++) {
      const int row = wr * 128 + mfp * 16 + lr;
      af[mfp] = *(const bf16x8*)(sa + row * 128 + ((hi ^ (row & 7)) * 16));
    }
#pragma unroll
    for (int nf = 0; nf < 4; nf++) {
      const int row = wc * 64 + nf * 16 + lr;
      bfr[nf] = *(const bf16x8*)(sb + row * 128 + ((hi ^ (row & 7)) * 16));
    }
    __builtin_amdgcn_s_setprio(1);
#pragma unroll
    for (int mfp = 0; mfp < 4; mfp++)
#pragma unroll
      for (int nf = 0; nf < 4; nf++)
        acc[mfp][nf] = mfma16(af[mfp], bfr[nf], acc[mfp][nf]);
    __builtin_amdgcn_s_setprio(0);
    // ---- group 1: M-half 1, kk=0 (reuse bfr) ----
#pragma unroll
    for (int mfp = 0; mfp < 4; mfp++) {
      const int row = wr * 128 + 64 + mfp * 16 + lr;
      af[mfp] = *(const bf16x8*)(sa + row * 128 + ((hi ^ (row & 7)) * 16));
    }
    __builtin_amdgcn_s_setprio(1);
#pragma unroll
    for (int mfp = 0; mfp < 4; mfp++)
#pragma unroll
      for (int nf = 0; nf < 4; nf++)
        acc[4 + mfp][nf] = mfma16(af[mfp], bfr[nf], acc[4 + mfp][nf]);
    __builtin_amdgcn_s_setprio(0);
    // ---- group 2: M-half 0, kk=1 ----
#pragma unroll
    for (int mfp = 0; mfp < 4; mfp++) {
      const int row = wr * 128 + mfp * 16 + lr;
      af[mfp] = *(const bf16x8*)(sa + row * 128 + (((4 + hi) ^ (row & 7)) * 16));
    }
#pragma unroll
    for (int nf = 0; nf < 4; nf++) {
      const int row = wc * 64 + nf * 16 + lr;
      bfr[nf] = *(const bf16x8*)(sb + row * 128 + (((4 + hi) ^ (row & 7)) * 16));
    }
    __builtin_amdgcn_s_setprio(1);
#pragma unroll
    for (int mfp = 0; mfp < 4; mfp++)
#pragma unroll
      for (int nf = 0; nf < 4; nf++)
        acc[mfp][nf] = mfma16(af[mfp], bfr[nf], acc[mfp][nf]);
    __builtin_amdgcn_s_setprio(0);
    // ---- group 3: M-half 1, kk=1 (reuse bfr) ----
#pragma unroll
    for (int mfp = 0; mfp < 4; mfp++) {
      const int row = wr * 128 + 64 + mfp * 16 + lr;
      af[mfp] = *(const bf16x8*)(sa + row * 128 + (((4 + hi) ^ (row & 7)) * 16));
    }
    __builtin_amdgcn_s_setprio(1);
#pragma unroll
    for (int mfp = 0; mfp < 4; mfp++)
#pragma unroll
      for (int nf = 0; nf < 4; nf++)
        acc[4 + mfp][nf] = mfma16(af[mfp], bfr[nf], acc[4 + mfp][nf]);
    __builtin_amdgcn_s_setprio(0);
    // WAR: all waves' tile-t reads consumed before buf[t&1] is re-staged
    __builtin_amdgcn_sched_barrier(0);
    __builtin_amdgcn_s_barrier();
    __builtin_amdgcn_sched_barrier(0);
  }
  const int rg = hi * 4, cl = lr;
  if (QKVPACK && (bn >> 10) == 1) {
    // K -> kp[bh][s][64]
    bf16* kp_ = pr.p[0];
    const int b_ = bm >> 11;
    const int sb_ = (bm & 2047) + wr * 128;
#pragma unroll
    for (int mf = 0; mf < 8; mf++)
#pragma unroll
      for (int nf = 0; nf < 4; nf++) {
        const int col_loc = (bn & 1023) + wc * 64 + nf * 16 + cl;
        const int hh = col_loc >> 6, dd = col_loc & 63;
        bf16* base = kp_ + (size_t)(b_ * 16 + hh) * (KS * 64) + dd;
#pragma unroll
        for (int i = 0; i < 4; i++)
          base[(size_t)(sb_ + mf * 16 + rg + i) * 64] = (bf16)acc[mf][nf][i];
      }
  } else if (QKVPACK && (bn >> 10) == 2) {
    // V -> vt[bh][d][s], slot-permuted (see derivation above)
    bf16* vt_ = pr.p[1];
    const int b_ = bm >> 11;
    const int sb_ = (bm & 2047) + wr * 128;
    const int pib = ((hi & 2) << 3) | ((hi & 1) << 3);
#pragma unroll
    for (int mf = 0; mf < 8; mf++) {
      const int s_hi = sb_ + (mf >> 2) * 64;
      const int pibase = pib | ((mf & 2) << 4) | ((mf & 1) << 2);
#pragma unroll
      for (int nf = 0; nf < 4; nf++) {
        const int col_loc = (bn & 1023) + wc * 64 + nf * 16 + cl;
        const int hh = col_loc >> 6, dd = col_loc & 63;
        bf16x4 o;
#pragma unroll
        for (int i = 0; i < 4; i++) o[i] = (bf16)acc[mf][nf][i];
        *(bf16x4*)(vt_ + (size_t)(b_ * 16 + hh) * (64 * KS) +
                   (size_t)dd * KS + s_hi + pibase) = o;
      }
    }
  } else if (SPLITK) {
    bf16* P = pr.p[z];
#pragma unroll
    for (int mf = 0; mf < 8; mf++)
#pragma unroll
      for (int nf = 0; nf < 4; nf++) {
        const int col = bn + wc * 64 + nf * 16 + cl;
#pragma unroll
        for (int i = 0; i < 4; i++) {
          const int row = bm + wr * 128 + mf * 16 + rg + i;
          P[(size_t)row * N + col] = (bf16)acc[mf][nf][i];
        }
      }
  } else {
#pragma unroll
    for (int mf = 0; mf < 8; mf++)
#pragma unroll
      for (int nf = 0; nf < 4; nf++) {
        const int col = bn + wc * 64 + nf * 16 + cl;
        float bv = 0.f;
        if (HAS_BIAS) bv = bias[col];
#pragma unroll
        for (int i = 0; i < 4; i++) {
          const int row = bm + wr * 128 + mf * 16 + rg + i;
          float v = acc[mf][nf][i] + bv;
          if (RELU) v = fmaxf(v, 0.f);
          C[(size_t)row * N + col] = (OUT_T)v;
        }
      }
  }
}

// ---------------- old 2-phase GEMM (kept for Wo: short K, N=1024) ----------------
template <typename OUT_T, bool RELU, bool HAS_BIAS, int BN>
__global__ __launch_bounds__(256) void gemm_bt(const bf16* __restrict__ A,
                                               const bf16* __restrict__ BT,
                                               OUT_T* __restrict__ C,
                                               const float* __restrict__ bias,
                                               int M, int N, int K) {
  constexpr int NF = BN / 32;
  __shared__ __align__(16) bf16 sa[2][128 * 32];
  __shared__ __align__(16) bf16 sb[2][BN * 32];
  const int t = threadIdx.x, lane = t & 63, w = t >> 6;
  const int gx = gridDim.x;
  const int nwg = gx * gridDim.y;
  int flat = blockIdx.y * gx + blockIdx.x;
  if ((nwg & 7) == 0) flat = (flat & 7) * (nwg >> 3) + (flat >> 3);
  const int bn = (flat % gx) * BN;
  const int bm = (flat / gx) * 128;
  const int wr = w >> 1, wc = w & 1;
  const int wcol = wc * (BN / 2);
  const int lr = lane & 15, lk = (lane >> 4) * 8;
  const int srow = w * 16 + (lane >> 2);
  const int scol = (lane & 3) * 8;
  f32x4 acc[4][NF] = {};
  const int NT = K >> 5;
  auto stage = [&](int kt, int buf) {
#pragma unroll
    for (int i = 0; i < 2; i++)
      g2l16(A + (size_t)(bm + i * 64 + srow) * K + kt * 32 + scol,
            &sa[buf][(i * 64 + w * 16) * 32]);
#pragma unroll
    for (int i = 0; i < BN / 64; i++)
      g2l16(BT + (size_t)(bn + i * 64 + srow) * K + kt * 32 + scol,
            &sb[buf][(i * 64 + w * 16) * 32]);
  };
  stage(0, 0);
  int cur = 0;
  for (int kt = 0; kt < NT; kt++) {
    __syncthreads();
    if (kt + 1 < NT) stage(kt + 1, cur ^ 1);
    bf16x8 af[4], bfr[NF];
#pragma unroll
    for (int m = 0; m < 4; m++)
      af[m] = *(const bf16x8*)&sa[cur][(wr * 64 + m * 16 + lr) * 32 + lk];
#pragma unroll
    for (int n = 0; n < NF; n++)
      bfr[n] = *(const bf16x8*)&sb[cur][(wcol + n * 16 + lr) * 32 + lk];
#pragma unroll
    for (int m = 0; m < 4; m++)
#pragma unroll
      for (int n = 0; n < NF; n++)
        acc[m][n] = mfma16(af[m], bfr[n], acc[m][n]);
    cur ^= 1;
  }
  const int rg = (lane >> 4) * 4, cl = lane & 15;
#pragma unroll
  for (int m = 0; m < 4; m++)
#pragma unroll
    for (int n = 0; n < NF; n++) {
      const int col = bn + wcol + n * 16 + cl;
      float bv = 0.f;
      if (HAS_BIAS) bv = bias[col];
#pragma unroll
      for (int i = 0; i < 4; i++) {
        const int row = bm + wr * 64 + m * 16 + rg + i;
        float v = acc[m][n][i] + bv;
        if (RELU) v = fmaxf(v, 0.f);
        C[(size_t)row * N + col] = (OUT_T)v;
      }
    }
}

// ---------------- flash attention: swapped QK^T, in-register P, ring-4 ----------
// (R18-proven.) 8 waves x 16 q-rows (512 thr), QBLK=128/block -> staging, LDS
// reads, MFMA, TRANS all identical totals to the 4-wave version, but 16 waves/CU
// for TLP overlap of the serial QK->exp->PV chain. 1 K + 1 V load/lane/stage.
// Sync (ring-4, depth-3): RAW head vmcnt(4|2|0) + s_barrier; WAR: stage(tt+3)
// issued after the barrier all waves pass having consumed tile tt-1's reads.
__global__ __launch_bounds__(512) void attn_kernel(const bf16* __restrict__ qkv,
                                                   const bf16* __restrict__ kp,
                                                   const bf16* __restrict__ vt,
                                                   bf16* __restrict__ ctx) {
  __shared__ __align__(16) bf16 ksm[4][64 * 64];
  __shared__ __align__(16) bf16 vsm[4][64 * 64];
  const int t = threadIdx.x, lane = t & 63, w = t >> 6;   // w in [0,8)
  const int flat = blockIdx.y * 16 + blockIdx.x;
  const int xcd = flat & 7, jj = flat >> 3;
  const int bh = xcd + 8 * (jj >> 4);              // all 16 q-blocks of a head on 1 XCD
  const int qb = jj & 15;
  const int b = bh >> 4, h = bh & 15;
  const int qbase = qb * 128 + w * 16;
  const int lr = lane & 15, hi = lane >> 4;
  const int lk = hi * 8, rg = hi * 4, cl = lr;

  // Q fragments, pre-scaled by 0.125*log2(e) so scores feed v_exp_f32 directly
  bf16x8 aq[2];
#pragma unroll
  for (int kk = 0; kk < 2; kk++) {
    bf16x8 v = *reinterpret_cast<const bf16x8*>(
        &qkv[(size_t)(b * KS + qbase + lr) * KQKVN + h * 64 + kk * 32 + lk]);
#pragma unroll
    for (int e = 0; e < 8; e++) v[e] = (bf16)((float)v[e] * 0.18033688f);
    aq[kk] = v;
  }
  bf16x8 ones;
#pragma unroll
  for (int j = 0; j < 8; j++) ones[j] = (bf16)1.0f;

  const bf16* kpb = kp + (size_t)bh * KS * 64;
  const bf16* vtb = vt + (size_t)bh * 64 * KS;

  // 512 lanes cover each 8KB (64x64 bf16) tile in one shot: 1 K + 1 V load/lane
  auto stageKV = [&](int tt) {
    const int kt0 = tt * 64;
    bf16* kd = &ksm[tt & 3][0] + w * 512;            // wave-uniform dest
    bf16* vd = &vsm[tt & 3][0] + w * 512;
    const int q = w * 1024 + (lane << 4);            // this lane's LDS byte
    const int row = q >> 7;
    const int slot = ((q >> 4) & 7) ^ (row & 7);     // inverse-swizzled source
    g2l16(kpb + (size_t)(kt0 + row) * 64 + slot * 8, kd);
    g2l16(vtb + (size_t)row * KS + kt0 + slot * 8,   vd);
  };

  f32x4 accd[4] = {};
  f32x4 lsumv = {};

  stageKV(0); stageKV(1); stageKV(2);                 // 6 loads/lane in flight
  const int NT = KS / 64;                             // 32
  for (int tt = 0; tt < NT; tt++) {
    const int rem = NT - 1 - tt;
    if (rem >= 2)      asm volatile("s_waitcnt vmcnt(4)" ::: "memory");
    else if (rem == 1) asm volatile("s_waitcnt vmcnt(2)" ::: "memory");
    else               asm volatile("s_waitcnt vmcnt(0)" ::: "memory");
    __builtin_amdgcn_sched_barrier(0);
    __builtin_amdgcn_s_barrier();                     // RAW: tile tt ready
    __builtin_amdgcn_sched_barrier(0);
    if (tt + 3 < NT) stageKV(tt + 3);
    const char* kb = (const char*)&ksm[tt & 3][0];
    const char* vb = (const char*)&vsm[tt & 3][0];
    // K fragments (A-operand: rows = keys)
    bf16x8 bk[4][2];
#pragma unroll
    for (int n = 0; n < 4; n++)
#pragma unroll
      for (int kk = 0; kk < 2; kk++) {
        const int row = n * 16 + lr;
        bk[n][kk] = *(const bf16x8*)(kb + row * 128 +
                                     ((kk * 64 + hi * 16) ^ ((row & 7) << 4)));
      }
    // swapped QK^T: D[key][q] — lane holds 16 keys for its own q = lr
    f32x4 sc[4] = {};
    __builtin_amdgcn_s_setprio(1);
#pragma unroll
    for (int n = 0; n < 4; n++)
#pragma unroll
      for (int kk = 0; kk < 2; kk++)
        sc[n] = mfma16(bk[n][kk], aq[kk], sc[n]);
    __builtin_amdgcn_s_setprio(0);
    // p = 2^score in regs; build PV A-fragments directly
    bf16x8 pa[2];
    {
      float p[4][4];
#pragma unroll
      for (int n = 0; n < 4; n++)
#pragma unroll
        for (int i = 0; i < 4; i++)
          p[n][i] = exp2_hw(sc[n][i]);
#pragma unroll
      for (int kk = 0; kk < 2; kk++) {
        bf16x8 v;
#pragma unroll
        for (int j = 0; j < 8; j++) v[j] = (bf16)p[kk * 2 + (j >> 2)][j & 3];
        pa[kk] = v;
      }
    }
    // V fragments (B-operand, slot-permuted rows) + PV + MFMA row-sums
    bf16x8 bv[4][2];
#pragma unroll
    for (int dt = 0; dt < 4; dt++)
#pragma unroll
      for (int kk = 0; kk < 2; kk++) {
        const int row = dt * 16 + lr;
        bv[dt][kk] = *(const bf16x8*)(vb + row * 128 +
                                      ((kk * 64 + hi * 16) ^ ((row & 7) << 4)));
      }
    __builtin_amdgcn_s_setprio(1);
#pragma unroll
    for (int dt = 0; dt < 4; dt++)
#pragma unroll
      for (int kk = 0; kk < 2; kk++)
        accd[dt] = mfma16(pa[kk], bv[dt][kk], accd[dt]);
    lsumv = mfma16(pa[0], ones, lsumv);
    lsumv = mfma16(pa[1], ones, lsumv);
    __builtin_amdgcn_s_setprio(0);
  }
  // lsumv in C-layout: lane's lsumv[i] = rowsum for q = rg+i
#pragma unroll
  for (int dt = 0; dt < 4; dt++)
#pragma unroll
    for (int i = 0; i < 4; i++)
      ctx[(size_t)(b * KS + qbase + rg + i) * KD + h * 64 + dt * 16 + cl] =
          (bf16)(accd[dt][i] / lsumv[i]);
}

// ---------------- residual add + LayerNorm ----------------
// a + b -> LN; each of a, b, out independently bf16 or f32
template <bool ABF, bool BBF, bool OBF>
__global__ __launch_bounds__(256) void ln_kernel(const void* __restrict__ aptr,
                                                 const void* __restrict__ bptr,
                                                 const float* __restrict__ g,
                                                 const float* __restrict__ bet,
                                                 void* __restrict__ outp) {
  const int row = blockIdx.x;
  const int t = threadIdx.x;
  const int lane = t & 63, wid = t >> 6;
  float v[4];
  {
    float a[4], bb[4];
    if (ABF) {
      bf16x4 av = *reinterpret_cast<const bf16x4*>(
          (const bf16*)aptr + (size_t)row * KD + t * 4);
#pragma unroll
      for (int j = 0; j < 4; j++) a[j] = (float)av[j];
    } else {
      f32x4 av = *reinterpret_cast<const f32x4*>(
          (const float*)aptr + (size_t)row * KD + t * 4);
#pragma unroll
      for (int j = 0; j < 4; j++) a[j] = av[j];
    }
    if (BBF) {
      bf16x4 bv = *reinterpret_cast<const bf16x4*>(
          (const bf16*)bptr + (size_t)row * KD + t * 4);
#pragma unroll
      for (int j = 0; j < 4; j++) bb[j] = (float)bv[j];
    } else {
      f32x4 bv = *reinterpret_cast<const f32x4*>(
          (const float*)bptr + (size_t)row * KD + t * 4);
#pragma unroll
      for (int j = 0; j < 4; j++) bb[j] = bv[j];
    }
#pragma unroll
    for (int j = 0; j < 4; j++) v[j] = a[j] + bb[j];
  }
  float s = 0.f, s2 = 0.f;
#pragma unroll
  for (int j = 0; j < 4; j++) { s += v[j]; s2 += v[j] * v[j]; }
#pragma unroll
  for (int off = 32; off; off >>= 1) {
    s += __shfl_xor(s, off, 64);
    s2 += __shfl_xor(s2, off, 64);
  }
  __shared__ float red[8];
  if (lane == 0) { red[wid] = s; red[wid + 4] = s2; }
  __syncthreads();
  s = red[0] + red[1] + red[2] + red[3];
  s2 = red[4] + red[5] + red[6] + red[7];
  const float mu = s * (1.f / KD);
  const float var = s2 * (1.f / KD) - mu * mu;
  const float rs = rsqrtf(var + 1e-5f);
  if (OBF) {
    bf16x4 o;
#pragma unroll
    for (int j = 0; j < 4; j++)
      o[j] = (bf16)((v[j] - mu) * rs * g[t * 4 + j] + bet[t * 4 + j]);
    *reinterpret_cast<bf16x4*>((bf16*)outp + (size_t)row * KD + t * 4) = o;
  } else {
    f32x4 o;
#pragma unroll
    for (int j = 0; j < 4; j++)
      o[j] = (v[j] - mu) * rs * g[t * 4 + j] + bet[t * 4 + j];
    *reinterpret_cast<f32x4*>((float*)outp + (size_t)row * KD + t * 4) = o;
  }
}

// ---------------- LN2 fused with FFN2 split-K reduce + bias ----------------
// out = LN(h + p0+p1+p2+p3 + b2)
__global__ __launch_bounds__(256) void ln2_fused_kernel(const bf16* __restrict__ hh,
                                                        const bf16* __restrict__ p0,
                                                        const bf16* __restrict__ p1,
                                                        const bf16* __restrict__ p2,
                                                        const bf16* __restrict__ p3,
                                                        const float* __restrict__ b2,
                                                        const float* __restrict__ g,
                                                        const float* __restrict__ bet,
                                                        float* __restrict__ outp) {
  const int row = blockIdx.x;
  const int t = threadIdx.x;
  const int lane = t & 63, wid = t >> 6;
  const size_t base = (size_t)row * KD + t * 4;
  bf16x4 hv = *(const bf16x4*)(hh + base);
  bf16x4 a0 = *(const bf16x4*)(p0 + base);
  bf16x4 a1 = *(const bf16x4*)(p1 + base);
  bf16x4 a2 = *(const bf16x4*)(p2 + base);
  bf16x4 a3 = *(const bf16x4*)(p3 + base);
  f32x4 bv = *(const f32x4*)(b2 + t * 4);
  float v[4];
#pragma unroll
  for (int j = 0; j < 4; j++)
    v[j] = (float)hv[j] + (float)a0[j] + (float)a1[j] + (float)a2[j] + (float)a3[j] + bv[j];
  float s = 0.f, s2 = 0.f;
#pragma unroll
  for (int j = 0; j < 4; j++) { s += v[j]; s2 += v[j] * v[j]; }
#pragma unroll
  for (int off = 32; off; off >>= 1) {
    s += __shfl_xor(s, off, 64);
    s2 += __shfl_xor(s2, off, 64);
  }
  __shared__ float red[8];
  if (lane == 0) { red[wid] = s; red[wid + 4] = s2; }
  __syncthreads();
  s = red[0] + red[1] + red[2] + red[3];
  s2 = red[4] + red[5] + red[6] + red[7];
  const float mu = s * (1.f / KD);
  const float var = s2 * (1.f / KD) - mu * mu;
  const float rs = rsqrtf(var + 1e-5f);
  f32x4 o;
#pragma unroll
  for (int j = 0; j < 4; j++)
    o[j] = (v[j] - mu) * rs * g[t * 4 + j] + bet[t * 4 + j];
  *reinterpret_cast<f32x4*>(outp + base) = o;
}

extern "C" void kernel_launch(void* const* d_in, const int* in_sizes, int n_in,
                              void* d_out, int out_size, void* d_ws, size_t ws_size,
                              hipStream_t stream) {
  const float* x     = (const float*)d_in[0];
  const float* wq    = (const float*)d_in[1];
  const float* wk    = (const float*)d_in[2];
  const float* wv    = (const float*)d_in[3];
  const float* wo    = (const float*)d_in[4];
  const float* w1    = (const float*)d_in[5];
  const float* b1    = (const float*)d_in[6];
  const float* w2    = (const float*)d_in[7];
  const float* b2    = (const float*)d_in[8];
  const float* ln1g  = (const float*)d_in[9];
  const float* ln1b  = (const float*)d_in[10];
  const float* ln2g  = (const float*)d_in[11];
  const float* ln2b  = (const float*)d_in[12];
  float* out = (float*)d_out;

  char* ws = (char*)d_ws;
  // Alias audit (write -> read order; every region rewritten before read):
  // [0     , 8.39M)  x_bf (1->2,6) -> FFN2 pr0 (8->9)
  // [8.39M ,14.68M)  wqkvT (1->2) ; h_bf [8.39,16.78) (6->7,9)
  // [14.68M,16.78M)  woT (1->5)
  // [16.78M,25.17M)  w1T (1->7) -> FFN2 pr1 (8->9)
  // [25.17M,33.55M)  w2T (1->8)
  // [33.55M,58.72M)  qkv Q-cols (2->4) -> ffn1 [33.55,67.11) (7->8)
  // [58.72M,67.11M)  kp (2->4)
  // [67.11M,75.50M)  vt (2->4) -> FFN2 pr2 (8->9)
  // [75.50M,83.89M)  ctx (4->5) -> FFN2 pr3 (8->9)
  // [83.89M,92.27M)  proj_bf (5->6)
  bf16*  x_bf   = (bf16*)(ws + 0);
  bf16*  wqkvT  = (bf16*)(ws + 8388608);
  bf16*  woT    = (bf16*)(ws + 14680064);
  bf16*  w1T    = (bf16*)(ws + 16777216);
  bf16*  w2T    = (bf16*)(ws + 25165824);
  bf16*  qkv    = (bf16*)(ws + 33554432);
  bf16*  kp     = (bf16*)(ws + 58720256);
  bf16*  vt     = (bf16*)(ws + 67108864);
  bf16*  ctx    = (bf16*)(ws + 75497472);
  bf16*  proj_bf= (bf16*)(ws + 83886080);
  bf16*  h_bf   = (bf16*)(ws + 8388608);
  bf16*  ffn1   = qkv;
  P4 pk;                                   // QKV pack targets
  pk.p[0] = kp; pk.p[1] = vt; pk.p[2] = nullptr; pk.p[3] = nullptr;
  P4 pr;                                   // FFN2 split-K partials
  pr.p[0] = (bf16*)(ws + 0);
  pr.p[1] = (bf16*)(ws + 16777216);
  pr.p[2] = (bf16*)(ws + 67108864);
  pr.p[3] = (bf16*)(ws + 75497472);
  P4 pzero = {};

  // 1) conversions / transposes
  cvt_bf16_kernel<<<dim3(KM * KD / 1024), 256, 0, stream>>>(x, x_bf, KM * KD);
  WT4 jobs;
  jobs.src[0] = wq; jobs.src[1] = wk; jobs.src[2] = wv; jobs.src[3] = wo;
  jobs.dst[0] = wqkvT;
  jobs.dst[1] = wqkvT + 1024 * 1024;
  jobs.dst[2] = wqkvT + 2048 * 1024;
  jobs.dst[3] = woT;
  wtrans4_kernel<<<dim3(32, 32, 4), 256, 0, stream>>>(jobs);
  wtrans_big_kernel<<<dim3(128, 32, 2), 256, 0, stream>>>(w1, w1T, w2, w2T);

  // 2) QKV projection with fused K/V repack (Q->qkv, K->kp, V->vt permuted)
  gemm8p<bf16, false, false, false, true>
      <<<dim3(KQKVN / 256, KM / 256, 1), 512, 131072, stream>>>(
      x_bf, wqkvT, qkv, pk, nullptr, KM, KQKVN, KD, KD);

  // 4) flash attention (8 waves x 16 q-rows, ring-4, 16 waves/CU)
  attn_kernel<<<dim3(KS / 128, KB * KH), 512, 0, stream>>>(qkv, kp, vt, ctx);

  // 5) Wo projection: 2-phase BN=64 (512 blocks) -> proj_bf (bf16)
  gemm_bt<bf16, false, false, 64><<<dim3(KD / 64, KM / 128), 256, 0, stream>>>(
      ctx, woT, proj_bf, nullptr, KM, KD, KD);

  // 6) LN1: h = LN(x_bf + proj_bf) -> h_bf
  ln_kernel<true, true, true><<<dim3(KM), 256, 0, stream>>>(
      x_bf, proj_bf, ln1g, ln1b, h_bf);

  // 7) FFN1: 4-phase deep-pipeline, 256 blocks
  gemm8p<bf16, true, true, false, false>
      <<<dim3(KDF / 256, KM / 256, 1), 512, 131072, stream>>>(
      h_bf, w1T, ffn1, pzero, b1, KM, KDF, KD, KD);

  // 8) FFN2: split-K=4 (4x16x4 = 256 blocks, Kslice=1024) -> bf16 partials
  gemm8p<bf16, false, false, true, false>
      <<<dim3(KD / 256, KM / 256, 4), 512, 131072, stream>>>(
      ffn1, w2T, (bf16*)nullptr, pr, nullptr, KM, KD, KDF, KDF / 4);

  // 9) LN2 fused with split-K reduce + bias
  ln2_fused_kernel<<<dim3(KM), 256, 0, stream>>>(
      h_bf, pr.p[0], pr.p[1], pr.p[2], pr.p[3], b2, ln2g, ln2b, out);
}

// Round 21
// 211.206 us; speedup vs baseline: 1.0601x; 1.0006x over previous
//
#include <hip/hip_runtime.h>
#include <hip/hip_bf16.h>

typedef __bf16 bf16;
typedef __bf16 bf16x4 __attribute__((ext_vector_type(4)));
typedef __bf16 bf16x8 __attribute__((ext_vector_type(8)));
typedef float  f32x4  __attribute__((ext_vector_type(4)));

#define KB 2
#define KS 2048
#define KD 1024
#define KH 16
#define KM (KB*KS)          // 4096 token rows
#define KQKVN 3072
#define KDF 4096

__device__ __forceinline__ f32x4 mfma16(bf16x8 a, bf16x8 b, f32x4 c) {
  return __builtin_amdgcn_mfma_f32_16x16x32_bf16(a, b, c, 0, 0, 0);
}

// raw v_exp_f32: computes 2^x (one TRANS op, no ln2 mul)
__device__ __forceinline__ float exp2_hw(float x) {
  float r;
  asm("v_exp_f32 %0, %1" : "=v"(r) : "v"(x));
  return r;
}

// async global->LDS, 16B per lane; LDS dest wave-uniform (HW adds lane*16)
__device__ __forceinline__ void g2l16(const bf16* g, bf16* l) {
  __builtin_amdgcn_global_load_lds(
      (const __attribute__((address_space(1))) unsigned int*)g,
      (__attribute__((address_space(3))) unsigned int*)l, 16, 0, 0);
}

// ---------------- fp32 -> bf16 elementwise ----------------
__global__ __launch_bounds__(256) void cvt_bf16_kernel(const float* __restrict__ in,
                                                       bf16* __restrict__ out, int n) {
  int i = (blockIdx.x * 256 + threadIdx.x) * 4;
  if (i >= n) return;
  f32x4 v = *reinterpret_cast<const f32x4*>(in + i);
  bf16x4 o;
  o[0] = (bf16)v[0]; o[1] = (bf16)v[1]; o[2] = (bf16)v[2]; o[3] = (bf16)v[3];
  *reinterpret_cast<bf16x4*>(out + i) = o;
}

// ---------------- fused W[K][N] f32 -> WT[N][K] bf16 transposes ----------------
struct WT4 { const float* src[4]; bf16* dst[4]; };

__global__ __launch_bounds__(256) void wtrans4_kernel(WT4 jobs) {
  __shared__ float tile[32][33];
  const float* W = jobs.src[blockIdx.z];
  bf16* WT = jobs.dst[blockIdx.z];
  const int n0 = blockIdx.x * 32, k0 = blockIdx.y * 32;
  const int tx = threadIdx.x & 31, ty = threadIdx.x >> 5;
#pragma unroll
  for (int j = ty; j < 32; j += 8) tile[j][tx] = W[(size_t)(k0 + j) * 1024 + n0 + tx];
  __syncthreads();
#pragma unroll
  for (int j = ty; j < 32; j += 8)
    WT[(size_t)(n0 + j) * 1024 + k0 + tx] = (bf16)tile[tx][j];
}

__global__ __launch_bounds__(256) void wtrans_big_kernel(const float* __restrict__ w1,
                                                         bf16* __restrict__ w1T,
                                                         const float* __restrict__ w2,
                                                         bf16* __restrict__ w2T) {
  __shared__ float tile[32][33];
  const float* W; bf16* WT; int K, N, n0, k0;
  if (blockIdx.z == 0) {
    W = w1; WT = w1T; K = 1024; N = 4096;
    n0 = blockIdx.x * 32; k0 = blockIdx.y * 32;
  } else {
    W = w2; WT = w2T; K = 4096; N = 1024;
    n0 = blockIdx.y * 32; k0 = blockIdx.x * 32;
  }
  const int tx = threadIdx.x & 31, ty = threadIdx.x >> 5;
#pragma unroll
  for (int j = ty; j < 32; j += 8) tile[j][tx] = W[(size_t)(k0 + j) * N + n0 + tx];
  __syncthreads();
#pragma unroll
  for (int j = ty; j < 32; j += 8) WT[(size_t)(n0 + j) * K + k0 + tx] = (bf16)tile[tx][j];
}

// ---------------- 4-phase deep-pipeline GEMM: 256x256, BK=64, ring-2 -------------
// Minimal barriers: RAW phase-0 vmcnt(4)+barrier, WAR tile-end barrier.
// QKVPACK epilogue folds kvpack into the QKV GEMM: reg 0 = Q -> C (qkv, stride N),
// reg 1 = K -> kp[bh][s][64], reg 2 = V -> vt[bh][d][s] slot-permuted:
// key k = (mf&3)*16 + hi*4 + i -> pi = ((mf&2)<<4)|((hi&2)<<3)|((hi&1)<<3)|((mf&1)<<2)+i.
struct P4 { bf16* p[4]; };

template <typename OUT_T, bool RELU, bool HAS_BIAS, bool SPLITK, bool QKVPACK>
__global__ __launch_bounds__(512, 2) void gemm8p(const bf16* __restrict__ A,
                                                 const bf16* __restrict__ BT,
                                                 OUT_T* __restrict__ C, P4 pr,
                                                 const float* __restrict__ bias,
                                                 int M, int N, int K, int Kslice) {
  extern __shared__ __align__(16) bf16 sm[];      // [2][A 16384 | B 16384] elems
  const int tid = threadIdx.x, lane = tid & 63, w = tid >> 6;
  const int wr = w >> 2, wc = w & 3;
  const int gx = gridDim.x;
  const int nwg = gx * gridDim.y;
  int flat = blockIdx.y * gx + blockIdx.x;
  flat = (flat & 7) * (nwg >> 3) + (flat >> 3);   // XCD-chunked (nwg%8==0)
  const int bn = (flat % gx) * 256;
  const int bm = (flat / gx) * 256;
  const int z = blockIdx.z;
  const int NT = (SPLITK ? Kslice : K) >> 6;      // BK=64
  const int lr = lane & 15, hi = lane >> 4;
  const int sqrow = tid >> 3;                     // 0..63, row within quarter
  const int sslot = tid & 7;
  const bf16* Abase = A + (size_t)bm * K + (SPLITK ? z * Kslice : 0);
  const bf16* Bbase = BT + (size_t)bn * K + (SPLITK ? z * Kslice : 0);
  // LDS[row][slot] = G[row][slot ^ (row&7)] (16B chunks); dest lane-linear.
  auto stageQ = [&](int t, int p) {
    const int row = p * 64 + sqrow;
    const int col = (sslot ^ (row & 7)) * 8;
    bf16* dst = sm + (size_t)(t & 1) * 32768 + p * 4096 + w * 512;
    g2l16(Abase + (size_t)row * K + t * 64 + col, dst);
    g2l16(Bbase + (size_t)row * K + t * 64 + col, dst + 16384);
  };
  f32x4 acc[8][4] = {};
  stageQ(0, 0); stageQ(0, 1); stageQ(0, 2); stageQ(0, 3);   // 8 loads in flight
  for (int t = 0; t < NT; t++) {
    const char* sa = (const char*)(sm + (size_t)(t & 1) * 32768);
    const char* sb = sa + 32768;
    // head: issue Q0,Q1 of t+1, then wait for all tile-t loads
    if (t + 1 < NT) {
      stageQ(t + 1, 0);
      stageQ(t + 1, 1);
      asm volatile("s_waitcnt vmcnt(4)" ::: "memory");
    } else {
      asm volatile("s_waitcnt vmcnt(0)" ::: "memory");
    }
    __builtin_amdgcn_sched_barrier(0);
    __builtin_amdgcn_s_barrier();                 // RAW: tile t ready, all waves
    __builtin_amdgcn_sched_barrier(0);
    if (t + 1 < NT) { stageQ(t + 1, 2); stageQ(t + 1, 3); }
    bf16x8 af[4], bfr[4];
    // ---- group 0: M-half 0, kk=0 ----
#pragma unroll
    for (int mfp = 0; mfp < 4; mfp++) {
      const int row = wr * 128 + mfp * 16 + lr;
      af[mfp] = *(const bf16x8*)(sa + row * 128 + ((hi ^ (row & 7)) * 16));
    }
#pragma unroll
    for (int nf = 0; nf < 4; nf++) {
      const int row = wc * 64 + nf * 16 + lr;
      bfr[nf] = *(const bf16x8*)(sb + row * 128 + ((hi ^ (row & 7)) * 16));
    }
    __builtin_amdgcn_s_setprio(1);
#pragma unroll
    for (int mfp = 0; mfp < 4; mfp++)
#pragma unroll
      for (int nf = 0; nf < 4; nf++)
        acc[mfp][nf] = mfma16(af[mfp], bfr[nf], acc[mfp][nf]);
    __builtin_amdgcn_s_setprio(0);
    // ---- group 1: M-half 1, kk=0 (reuse bfr) ----
#pragma unroll
    for (int mfp = 0; mfp < 4; mfp++) {
      const int row = wr * 128 + 64 + mfp * 16 + lr;
      af[mfp] = *(const bf16x8*)(sa + row * 128 + ((hi ^ (row & 7)) * 16));
    }
    __builtin_amdgcn_s_setprio(1);
#pragma unroll
    for (int mfp = 0; mfp < 4; mfp++)
#pragma unroll
      for (int nf = 0; nf < 4; nf++)
        acc[4 + mfp][nf] = mfma16(af[mfp], bfr[nf], acc[4 + mfp][nf]);
    __builtin_amdgcn_s_setprio(0);
    // ---- group 2: M-half 0, kk=1 ----
#pragma unroll
    for (int mfp = 0; mfp < 4; mfp++) {
      const int row = wr * 128 + mfp * 16 + lr;
      af[mfp] = *(const bf16x8*)(sa + row * 128 + (((4 + hi) ^ (row & 7)) * 16));
    }
#pragma unroll
    for (int nf = 0; nf < 4; nf++) {
      const int row = wc * 64 + nf * 16 + lr;
      bfr[nf] = *(const bf16x8*)(sb + row * 128 + (((4 + hi) ^ (row & 7)) * 16));
    }
    __builtin_amdgcn_s_setprio(1);
#pragma unroll
    for (int mfp = 0; mfp < 4; mfp++)
#pragma unroll
      for (int nf = 0; nf < 4; nf++)
        acc[mfp][nf] = mfma16(af[mfp], bfr[nf], acc[mfp][nf]);
    __builtin_amdgcn_s_setprio(0);
    // ---- group 3: M-half 1, kk=1 (reuse bfr) ----
#pragma unroll
    for (int mfp = 0; mfp < 4; mfp++) {
      const int row = wr * 128 + 64 + mfp * 16 + lr;
      af[mfp] = *(const bf16x8*)(sa + row * 128 + (((4 + hi) ^ (row & 7)) * 16));
    }
    __builtin_amdgcn_s_setprio(1);
#pragma unroll
    for (int mfp = 0; mfp < 4; mfp++)
#pragma unroll
      for (int nf = 0; nf < 4; nf++)
        acc[4 + mfp][nf] = mfma16(af[mfp], bfr[nf], acc[4 + mfp][nf]);
    __builtin_amdgcn_s_setprio(0);
    // WAR: all waves' tile-t reads consumed before buf[t&1] is re-staged
    __builtin_amdgcn_sched_barrier(0);
    __builtin_amdgcn_s_barrier();
    __builtin_amdgcn_sched_barrier(0);
  }
  const int rg = hi * 4, cl = lr;
  if (QKVPACK && (bn >> 10) == 1) {
    // K -> kp[bh][s][64]
    bf16* kp_ = pr.p[0];
    const int b_ = bm >> 11;
    const int sb_ = (bm & 2047) + wr * 128;
#pragma unroll
    for (int mf = 0; mf < 8; mf++)
#pragma unroll
      for (int nf = 0; nf < 4; nf++) {
        const int col_loc = (bn & 1023) + wc * 64 + nf * 16 + cl;
        const int hh = col_loc >> 6, dd = col_loc & 63;
        bf16* base = kp_ + (size_t)(b_ * 16 + hh) * (KS * 64) + dd;
#pragma unroll
        for (int i = 0; i < 4; i++)
          base[(size_t)(sb_ + mf * 16 + rg + i) * 64] = (bf16)acc[mf][nf][i];
      }
  } else if (QKVPACK && (bn >> 10) == 2) {
    // V -> vt[bh][d][s], slot-permuted (see derivation above)
    bf16* vt_ = pr.p[1];
    const int b_ = bm >> 11;
    const int sb_ = (bm & 2047) + wr * 128;
    const int pib = ((hi & 2) << 3) | ((hi & 1) << 3);
#pragma unroll
    for (int mf = 0; mf < 8; mf++) {
      const int s_hi = sb_ + (mf >> 2) * 64;
      const int pibase = pib | ((mf & 2) << 4) | ((mf & 1) << 2);
#pragma unroll
      for (int nf = 0; nf < 4; nf++) {
        const int col_loc = (bn & 1023) + wc * 64 + nf * 16 + cl;
        const int hh = col_loc >> 6, dd = col_loc & 63;
        bf16x4 o;
#pragma unroll
        for (int i = 0; i < 4; i++) o[i] = (bf16)acc[mf][nf][i];
        *(bf16x4*)(vt_ + (size_t)(b_ * 16 + hh) * (64 * KS) +
                   (size_t)dd * KS + s_hi + pibase) = o;
      }
    }
  } else if (SPLITK) {
    bf16* P = pr.p[z];
#pragma unroll
    for (int mf = 0; mf < 8; mf++)
#pragma unroll
      for (int nf = 0; nf < 4; nf++) {
        const int col = bn + wc * 64 + nf * 16 + cl;
#pragma unroll
        for (int i = 0; i < 4; i++) {
          const int row = bm + wr * 128 + mf * 16 + rg + i;
          P[(size_t)row * N + col] = (bf16)acc[mf][nf][i];
        }
      }
  } else {
#pragma unroll
    for (int mf = 0; mf < 8; mf++)
#pragma unroll
      for (int nf = 0; nf < 4; nf++) {
        const int col = bn + wc * 64 + nf * 16 + cl;
        float bv = 0.f;
        if (HAS_BIAS) bv = bias[col];
#pragma unroll
        for (int i = 0; i < 4; i++) {
          const int row = bm + wr * 128 + mf * 16 + rg + i;
          float v = acc[mf][nf][i] + bv;
          if (RELU) v = fmaxf(v, 0.f);
          C[(size_t)row * N + col] = (OUT_T)v;
        }
      }
  }
}

// ---------------- old 2-phase GEMM (kept for Wo: short K, N=1024) ----------------
template <typename OUT_T, bool RELU, bool HAS_BIAS, int BN>
__global__ __launch_bounds__(256) void gemm_bt(const bf16* __restrict__ A,
                                               const bf16* __restrict__ BT,
                                               OUT_T* __restrict__ C,
                                               const float* __restrict__ bias,
                                               int M, int N, int K) {
  constexpr int NF = BN / 32;
  __shared__ __align__(16) bf16 sa[2][128 * 32];
  __shared__ __align__(16) bf16 sb[2][BN * 32];
  const int t = threadIdx.x, lane = t & 63, w = t >> 6;
  const int gx = gridDim.x;
  const int nwg = gx * gridDim.y;
  int flat = blockIdx.y * gx + blockIdx.x;
  if ((nwg & 7) == 0) flat = (flat & 7) * (nwg >> 3) + (flat >> 3);
  const int bn = (flat % gx) * BN;
  const int bm = (flat / gx) * 128;
  const int wr = w >> 1, wc = w & 1;
  const int wcol = wc * (BN / 2);
  const int lr = lane & 15, lk = (lane >> 4) * 8;
  const int srow = w * 16 + (lane >> 2);
  const int scol = (lane & 3) * 8;
  f32x4 acc[4][NF] = {};
  const int NT = K >> 5;
  auto stage = [&](int kt, int buf) {
#pragma unroll
    for (int i = 0; i < 2; i++)
      g2l16(A + (size_t)(bm + i * 64 + srow) * K + kt * 32 + scol,
            &sa[buf][(i * 64 + w * 16) * 32]);
#pragma unroll
    for (int i = 0; i < BN / 64; i++)
      g2l16(BT + (size_t)(bn + i * 64 + srow) * K + kt * 32 + scol,
            &sb[buf][(i * 64 + w * 16) * 32]);
  };
  stage(0, 0);
  int cur = 0;
  for (int kt = 0; kt < NT; kt++) {
    __syncthreads();
    if (kt + 1 < NT) stage(kt + 1, cur ^ 1);
    bf16x8 af[4], bfr[NF];
#pragma unroll
    for (int m = 0; m < 4; m++)
      af[m] = *(const bf16x8*)&sa[cur][(wr * 64 + m * 16 + lr) * 32 + lk];
#pragma unroll
    for (int n = 0; n < NF; n++)
      bfr[n] = *(const bf16x8*)&sb[cur][(wcol + n * 16 + lr) * 32 + lk];
#pragma unroll
    for (int m = 0; m < 4; m++)
#pragma unroll
      for (int n = 0; n < NF; n++)
        acc[m][n] = mfma16(af[m], bfr[n], acc[m][n]);
    cur ^= 1;
  }
  const int rg = (lane >> 4) * 4, cl = lane & 15;
#pragma unroll
  for (int m = 0; m < 4; m++)
#pragma unroll
    for (int n = 0; n < NF; n++) {
      const int col = bn + wcol + n * 16 + cl;
      float bv = 0.f;
      if (HAS_BIAS) bv = bias[col];
#pragma unroll
      for (int i = 0; i < 4; i++) {
        const int row = bm + wr * 64 + m * 16 + rg + i;
        float v = acc[m][n][i] + bv;
        if (RELU) v = fmaxf(v, 0.f);
        C[(size_t)row * N + col] = (OUT_T)v;
      }
    }
}

// ---------------- flash attention: swapped QK^T, in-register P, ring-4 ----------
// 8 waves x 16 q-rows (512 thr), QBLK=128/block -> 16 waves/CU for TLP overlap
// of the serial QK->exp->PV chain. 1 K + 1 V load/lane/stage.
// Sync (ring-4, depth-3): RAW head vmcnt(4|2|0) + s_barrier; WAR: stage(tt+3)
// issued after the barrier all waves pass having consumed tile tt-1's reads.
__global__ __launch_bounds__(512) void attn_kernel(const bf16* __restrict__ qkv,
                                                   const bf16* __restrict__ kp,
                                                   const bf16* __restrict__ vt,
                                                   bf16* __restrict__ ctx) {
  __shared__ __align__(16) bf16 ksm[4][64 * 64];
  __shared__ __align__(16) bf16 vsm[4][64 * 64];
  const int t = threadIdx.x, lane = t & 63, w = t >> 6;   // w in [0,8)
  const int flat = blockIdx.y * 16 + blockIdx.x;
  const int xcd = flat & 7, jj = flat >> 3;
  const int bh = xcd + 8 * (jj >> 4);              // all 16 q-blocks of a head on 1 XCD
  const int qb = jj & 15;
  const int b = bh >> 4, h = bh & 15;
  const int qbase = qb * 128 + w * 16;
  const int lr = lane & 15, hi = lane >> 4;
  const int lk = hi * 8, rg = hi * 4, cl = lr;

  // Q fragments, pre-scaled by 0.125*log2(e) so scores feed v_exp_f32 directly
  bf16x8 aq[2];
#pragma unroll
  for (int kk = 0; kk < 2; kk++) {
    bf16x8 v = *reinterpret_cast<const bf16x8*>(
        &qkv[(size_t)(b * KS + qbase + lr) * KQKVN + h * 64 + kk * 32 + lk]);
#pragma unroll
    for (int e = 0; e < 8; e++) v[e] = (bf16)((float)v[e] * 0.18033688f);
    aq[kk] = v;
  }
  bf16x8 ones;
#pragma unroll
  for (int j = 0; j < 8; j++) ones[j] = (bf16)1.0f;

  const bf16* kpb = kp + (size_t)bh * KS * 64;
  const bf16* vtb = vt + (size_t)bh * 64 * KS;

  // 512 lanes cover each 8KB (64x64 bf16) tile in one shot: 1 K + 1 V load/lane
  auto stageKV = [&](int tt) {
    const int kt0 = tt * 64;
    bf16* kd = &ksm[tt & 3][0] + w * 512;            // wave-uniform dest
    bf16* vd = &vsm[tt & 3][0] + w * 512;
    const int q = w * 1024 + (lane << 4);            // this lane's LDS byte
    const int row = q >> 7;
    const int slot = ((q >> 4) & 7) ^ (row & 7);     // inverse-swizzled source
    g2l16(kpb + (size_t)(kt0 + row) * 64 + slot * 8, kd);
    g2l16(vtb + (size_t)row * KS + kt0 + slot * 8,   vd);
  };

  f32x4 accd[4] = {};
  f32x4 lsumv = {};

  stageKV(0); stageKV(1); stageKV(2);                 // 6 loads/lane in flight
  const int NT = KS / 64;                             // 32
  for (int tt = 0; tt < NT; tt++) {
    const int rem = NT - 1 - tt;
    if (rem >= 2)      asm volatile("s_waitcnt vmcnt(4)" ::: "memory");
    else if (rem == 1) asm volatile("s_waitcnt vmcnt(2)" ::: "memory");
    else               asm volatile("s_waitcnt vmcnt(0)" ::: "memory");
    __builtin_amdgcn_sched_barrier(0);
    __builtin_amdgcn_s_barrier();                     // RAW: tile tt ready
    __builtin_amdgcn_sched_barrier(0);
    if (tt + 3 < NT) stageKV(tt + 3);
    const char* kb = (const char*)&ksm[tt & 3][0];
    const char* vb = (const char*)&vsm[tt & 3][0];
    // K fragments (A-operand: rows = keys)
    bf16x8 bk[4][2];
#pragma unroll
    for (int n = 0; n < 4; n++)
#pragma unroll
      for (int kk = 0; kk < 2; kk++) {
        const int row = n * 16 + lr;
        bk[n][kk] = *(const bf16x8*)(kb + row * 128 +
                                     ((kk * 64 + hi * 16) ^ ((row & 7) << 4)));
      }
    // swapped QK^T: D[key][q] — lane holds 16 keys for its own q = lr
    f32x4 sc[4] = {};
    __builtin_amdgcn_s_setprio(1);
#pragma unroll
    for (int n = 0; n < 4; n++)
#pragma unroll
      for (int kk = 0; kk < 2; kk++)
        sc[n] = mfma16(bk[n][kk], aq[kk], sc[n]);
    __builtin_amdgcn_s_setprio(0);
    // p = 2^score in regs; build PV A-fragments directly
    bf16x8 pa[2];
    {
      float p[4][4];
#pragma unroll
      for (int n = 0; n < 4; n++)
#pragma unroll
        for (int i = 0; i < 4; i++)
          p[n][i] = exp2_hw(sc[n][i]);
#pragma unroll
      for (int kk = 0; kk < 2; kk++) {
        bf16x8 v;
#pragma unroll
        for (int j = 0; j < 8; j++) v[j] = (bf16)p[kk * 2 + (j >> 2)][j & 3];
        pa[kk] = v;
      }
    }
    // V fragments (B-operand, slot-permuted rows) + PV + MFMA row-sums
    bf16x8 bv[4][2];
#pragma unroll
    for (int dt = 0; dt < 4; dt++)
#pragma unroll
      for (int kk = 0; kk < 2; kk++) {
        const int row = dt * 16 + lr;
        bv[dt][kk] = *(const bf16x8*)(vb + row * 128 +
                                      ((kk * 64 + hi * 16) ^ ((row & 7) << 4)));
      }
    __builtin_amdgcn_s_setprio(1);
#pragma unroll
    for (int dt = 0; dt < 4; dt++)
#pragma unroll
      for (int kk = 0; kk < 2; kk++)
        accd[dt] = mfma16(pa[kk], bv[dt][kk], accd[dt]);
    lsumv = mfma16(pa[0], ones, lsumv);
    lsumv = mfma16(pa[1], ones, lsumv);
    __builtin_amdgcn_s_setprio(0);
  }
  // lsumv in C-layout: lane's lsumv[i] = rowsum for q = rg+i
#pragma unroll
  for (int dt = 0; dt < 4; dt++)
#pragma unroll
    for (int i = 0; i < 4; i++)
      ctx[(size_t)(b * KS + qbase + rg + i) * KD + h * 64 + dt * 16 + cl] =
          (bf16)(accd[dt][i] / lsumv[i]);
}

// ---------------- residual add + LayerNorm ----------------
// a + b -> LN; each of a, b, out independently bf16 or f32
template <bool ABF, bool BBF, bool OBF>
__global__ __launch_bounds__(256) void ln_kernel(const void* __restrict__ aptr,
                                                 const void* __restrict__ bptr,
                                                 const float* __restrict__ g,
                                                 const float* __restrict__ bet,
                                                 void* __restrict__ outp) {
  const int row = blockIdx.x;
  const int t = threadIdx.x;
  const int lane = t & 63, wid = t >> 6;
  float v[4];
  {
    float a[4], bb[4];
    if (ABF) {
      bf16x4 av = *reinterpret_cast<const bf16x4*>(
          (const bf16*)aptr + (size_t)row * KD + t * 4);
#pragma unroll
      for (int j = 0; j < 4; j++) a[j] = (float)av[j];
    } else {
      f32x4 av = *reinterpret_cast<const f32x4*>(
          (const float*)aptr + (size_t)row * KD + t * 4);
#pragma unroll
      for (int j = 0; j < 4; j++) a[j] = av[j];
    }
    if (BBF) {
      bf16x4 bv = *reinterpret_cast<const bf16x4*>(
          (const bf16*)bptr + (size_t)row * KD + t * 4);
#pragma unroll
      for (int j = 0; j < 4; j++) bb[j] = (float)bv[j];
    } else {
      f32x4 bv = *reinterpret_cast<const f32x4*>(
          (const float*)bptr + (size_t)row * KD + t * 4);
#pragma unroll
      for (int j = 0; j < 4; j++) bb[j] = bv[j];
    }
#pragma unroll
    for (int j = 0; j < 4; j++) v[j] = a[j] + bb[j];
  }
  float s = 0.f, s2 = 0.f;
#pragma unroll
  for (int j = 0; j < 4; j++) { s += v[j]; s2 += v[j] * v[j]; }
#pragma unroll
  for (int off = 32; off; off >>= 1) {
    s += __shfl_xor(s, off, 64);
    s2 += __shfl_xor(s2, off, 64);
  }
  __shared__ float red[8];
  if (lane == 0) { red[wid] = s; red[wid + 4] = s2; }
  __syncthreads();
  s = red[0] + red[1] + red[2] + red[3];
  s2 = red[4] + red[5] + red[6] + red[7];
  const float mu = s * (1.f / KD);
  const float var = s2 * (1.f / KD) - mu * mu;
  const float rs = rsqrtf(var + 1e-5f);
  if (OBF) {
    bf16x4 o;
#pragma unroll
    for (int j = 0; j < 4; j++)
      o[j] = (bf16)((v[j] - mu) * rs * g[t * 4 + j] + bet[t * 4 + j]);
    *reinterpret_cast<bf16x4*>((bf16*)outp + (size_t)row * KD + t * 4) = o;
  } else {
    f32x4 o;
#pragma unroll
    for (int j = 0; j < 4; j++)
      o[j] = (v[j] - mu) * rs * g[t * 4 + j] + bet[t * 4 + j];
    *reinterpret_cast<f32x4*>((float*)outp + (size_t)row * KD + t * 4) = o;
  }
}

// ---------------- LN2 fused with FFN2 split-K reduce + bias ----------------
// out = LN(h + p0+p1+p2+p3 + b2)
__global__ __launch_bounds__(256) void ln2_fused_kernel(const bf16* __restrict__ hh,
                                                        const bf16* __restrict__ p0,
                                                        const bf16* __restrict__ p1,
                                                        const bf16* __restrict__ p2,
                                                        const bf16* __restrict__ p3,
                                                        const float* __restrict__ b2,
                                                        const float* __restrict__ g,
                                                        const float* __restrict__ bet,
                                                        float* __restrict__ outp) {
  const int row = blockIdx.x;
  const int t = threadIdx.x;
  const int lane = t & 63, wid = t >> 6;
  const size_t base = (size_t)row * KD + t * 4;
  bf16x4 hv = *(const bf16x4*)(hh + base);
  bf16x4 a0 = *(const bf16x4*)(p0 + base);
  bf16x4 a1 = *(const bf16x4*)(p1 + base);
  bf16x4 a2 = *(const bf16x4*)(p2 + base);
  bf16x4 a3 = *(const bf16x4*)(p3 + base);
  f32x4 bv = *(const f32x4*)(b2 + t * 4);
  float v[4];
#pragma unroll
  for (int j = 0; j < 4; j++)
    v[j] = (float)hv[j] + (float)a0[j] + (float)a1[j] + (float)a2[j] + (float)a3[j] + bv[j];
  float s = 0.f, s2 = 0.f;
#pragma unroll
  for (int j = 0; j < 4; j++) { s += v[j]; s2 += v[j] * v[j]; }
#pragma unroll
  for (int off = 32; off; off >>= 1) {
    s += __shfl_xor(s, off, 64);
    s2 += __shfl_xor(s2, off, 64);
  }
  __shared__ float red[8];
  if (lane == 0) { red[wid] = s; red[wid + 4] = s2; }
  __syncthreads();
  s = red[0] + red[1] + red[2] + red[3];
  s2 = red[4] + red[5] + red[6] + red[7];
  const float mu = s * (1.f / KD);
  const float var = s2 * (1.f / KD) - mu * mu;
  const float rs = rsqrtf(var + 1e-5f);
  f32x4 o;
#pragma unroll
  for (int j = 0; j < 4; j++)
    o[j] = (v[j] - mu) * rs * g[t * 4 + j] + bet[t * 4 + j];
  *reinterpret_cast<f32x4*>(outp + base) = o;
}

extern "C" void kernel_launch(void* const* d_in, const int* in_sizes, int n_in,
                              void* d_out, int out_size, void* d_ws, size_t ws_size,
                              hipStream_t stream) {
  const float* x     = (const float*)d_in[0];
  const float* wq    = (const float*)d_in[1];
  const float* wk    = (const float*)d_in[2];
  const float* wv    = (const float*)d_in[3];
  const float* wo    = (const float*)d_in[4];
  const float* w1    = (const float*)d_in[5];
  const float* b1    = (const float*)d_in[6];
  const float* w2    = (const float*)d_in[7];
  const float* b2    = (const float*)d_in[8];
  const float* ln1g  = (const float*)d_in[9];
  const float* ln1b  = (const float*)d_in[10];
  const float* ln2g  = (const float*)d_in[11];
  const float* ln2b  = (const float*)d_in[12];
  float* out = (float*)d_out;

  char* ws = (char*)d_ws;
  // Alias audit (write -> read order; every region rewritten before read):
  // [0     , 8.39M)  x_bf (1->2,6) -> FFN2 pr0 (8->9)
  // [8.39M ,14.68M)  wqkvT (1->2) ; h_bf [8.39,16.78) (6->7,9)
  // [14.68M,16.78M)  woT (1->5)
  // [16.78M,25.17M)  w1T (1->7) -> FFN2 pr1 (8->9)
  // [25.17M,33.55M)  w2T (1->8)
  // [33.55M,58.72M)  qkv Q-cols (2->4) -> ffn1 [33.55,67.11) (7->8)
  // [58.72M,67.11M)  kp (2->4)
  // [67.11M,75.50M)  vt (2->4) -> FFN2 pr2 (8->9)
  // [75.50M,83.89M)  ctx (4->5) -> FFN2 pr3 (8->9)
  // [83.89M,92.27M)  proj_bf (5->6)
  bf16*  x_bf   = (bf16*)(ws + 0);
  bf16*  wqkvT  = (bf16*)(ws + 8388608);
  bf16*  woT    = (bf16*)(ws + 14680064);
  bf16*  w1T    = (bf16*)(ws + 16777216);
  bf16*  w2T    = (bf16*)(ws + 25165824);
  bf16*  qkv    = (bf16*)(ws + 33554432);
  bf16*  kp     = (bf16*)(ws + 58720256);
  bf16*  vt     = (bf16*)(ws + 67108864);
  bf16*  ctx    = (bf16*)(ws + 75497472);
  bf16*  proj_bf= (bf16*)(ws + 83886080);
  bf16*  h_bf   = (bf16*)(ws + 8388608);
  bf16*  ffn1   = qkv;
  P4 pk;                                   // QKV pack targets
  pk.p[0] = kp; pk.p[1] = vt; pk.p[2] = nullptr; pk.p[3] = nullptr;
  P4 pr;                                   // FFN2 split-K partials
  pr.p[0] = (bf16*)(ws + 0);
  pr.p[1] = (bf16*)(ws + 16777216);
  pr.p[2] = (bf16*)(ws + 67108864);
  pr.p[3] = (bf16*)(ws + 75497472);
  P4 pzero = {};

  // 1) conversions / transposes
  cvt_bf16_kernel<<<dim3(KM * KD / 1024), 256, 0, stream>>>(x, x_bf, KM * KD);
  WT4 jobs;
  jobs.src[0] = wq; jobs.src[1] = wk; jobs.src[2] = wv; jobs.src[3] = wo;
  jobs.dst[0] = wqkvT;
  jobs.dst[1] = wqkvT + 1024 * 1024;
  jobs.dst[2] = wqkvT + 2048 * 1024;
  jobs.dst[3] = woT;
  wtrans4_kernel<<<dim3(32, 32, 4), 256, 0, stream>>>(jobs);
  wtrans_big_kernel<<<dim3(128, 32, 2), 256, 0, stream>>>(w1, w1T, w2, w2T);

  // 2) QKV projection with fused K/V repack (Q->qkv, K->kp, V->vt permuted)
  gemm8p<bf16, false, false, false, true>
      <<<dim3(KQKVN / 256, KM / 256, 1), 512, 131072, stream>>>(
      x_bf, wqkvT, qkv, pk, nullptr, KM, KQKVN, KD, KD);

  // 4) flash attention (8 waves x 16 q-rows, ring-4, 16 waves/CU)
  attn_kernel<<<dim3(KS / 128, KB * KH), 512, 0, stream>>>(qkv, kp, vt, ctx);

  // 5) Wo projection: 2-phase BN=64 (512 blocks) -> proj_bf (bf16)
  gemm_bt<bf16, false, false, 64><<<dim3(KD / 64, KM / 128), 256, 0, stream>>>(
      ctx, woT, proj_bf, nullptr, KM, KD, KD);

  // 6) LN1: h = LN(x_bf + proj_bf) -> h_bf
  ln_kernel<true, true, true><<<dim3(KM), 256, 0, stream>>>(
      x_bf, proj_bf, ln1g, ln1b, h_bf);

  // 7) FFN1: 4-phase deep-pipeline, 256 blocks
  gemm8p<bf16, true, true, false, false>
      <<<dim3(KDF / 256, KM / 256, 1), 512, 131072, stream>>>(
      h_bf, w1T, ffn1, pzero, b1, KM, KDF, KD, KD);

  // 8) FFN2: split-K=4 (4x16x4 = 256 blocks, Kslice=1024) -> bf16 partials
  gemm8p<bf16, false, false, true, false>
      <<<dim3(KD / 256, KM / 256, 4), 512, 131072, stream>>>(
      ffn1, w2T, (bf16*)nullptr, pr, nullptr, KM, KD, KDF, KDF / 4);

  // 9) LN2 fused with split-K reduce + bias
  ln2_fused_kernel<<<dim3(KM), 256, 0, stream>>>(
      h_bf, pr.p[0], pr.p[1], pr.p[2], pr.p[3], b2, ln2g, ln2b, out);
}